// Round 1
// baseline (3796.279 us; speedup 1.0000x reference)
//
#include <hip/hip_runtime.h>

#define HH 80
#define WW 80
#define BB 4
#define CC 128
#define NPIX (BB*HH*WW)

// ---------------- weight transpose: OIHW -> [k*k][I][Opad], zero-padded ----------------
__global__ void transpose_w_k(const float* __restrict__ src, float* __restrict__ dst,
                              int O, int Opad, int I, int KK) {
    int n = KK * I * Opad;
    for (int idx = blockIdx.x * 256 + threadIdx.x; idx < n; idx += gridDim.x * 256) {
        int o = idx % Opad;
        int r = idx / Opad;
        int i = r % I;
        int t = r / I;
        dst[idx] = (o < O) ? src[(o * I + i) * KK + t] : 0.f;
    }
}

// ---------------- generic direct conv, NHWC (or NCHW) input, NHWC output ----------------
// block: 256 threads = OCPAD output channels x (256/OCPAD) pixel groups of PIX pixels.
// PPB = (256/OCPAD)*PIX must divide W (=20 for both instantiations).
template<int PIX, int OCPAD, bool NHWC_IN, bool BNSILU>
__global__ void conv_k(const float* __restrict__ in, int Cin_tot, int ci_base, int Cin,
                       const float* __restrict__ wT, const float* __restrict__ bias,
                       int Cout, int k, int pad, int dil,
                       const float* __restrict__ bn_g, const float* __restrict__ bn_b,
                       const float* __restrict__ bn_m, const float* __restrict__ bn_v,
                       float* __restrict__ out) {
    constexpr int PG  = 256 / OCPAD;
    constexpr int PPB = PG * PIX;   // 20
    int t  = threadIdx.x;
    int oc = t % OCPAD;
    int pg = t / OCPAD;
    int blk  = blockIdx.x;
    int nwb  = WW / PPB;            // 4
    int wblk = blk % nwb;
    int rest = blk / nwb;
    int h0 = rest % HH;
    int b  = rest / HH;
    int wbase = wblk * PPB + pg * PIX;

    float acc[PIX];
#pragma unroll
    for (int p = 0; p < PIX; p++) acc[p] = 0.f;

    for (int ky = 0; ky < k; ky++) {
        int yi = h0 + ky * dil - pad;
        if ((unsigned)yi >= (unsigned)HH) continue;
        const float* ib0;
        if (NHWC_IN) ib0 = in + ((size_t)(b * HH + yi) * WW) * Cin_tot + ci_base;
        else         ib0 = in + ((size_t)(b * Cin_tot + ci_base) * HH + yi) * WW;
        for (int kx = 0; kx < k; kx++) {
            int xib = wbase + kx * dil - pad;
            const float* wrow = wT + ((size_t)(ky * k + kx) * Cin) * OCPAD + oc;
            for (int ci = 0; ci < Cin; ci++) {
                float wv = wrow[(size_t)ci * OCPAD];
                const float* ip = NHWC_IN ? (ib0 + ci) : (ib0 + (size_t)ci * (HH * WW));
#pragma unroll
                for (int p = 0; p < PIX; p++) {
                    int xi = xib + p;
                    float xv = 0.f;
                    if ((unsigned)xi < (unsigned)WW)
                        xv = NHWC_IN ? ip[(size_t)xi * Cin_tot] : ip[xi];
                    acc[p] = fmaf(wv, xv, acc[p]);
                }
            }
        }
    }

    if (oc < Cout) {
        float bv = bias ? bias[oc] : 0.f;
        float scale = 1.f, shift = 0.f;
        if (BNSILU) {
            scale = bn_g[oc] / sqrtf(bn_v[oc] + 1e-5f);
            shift = bn_b[oc] - bn_m[oc] * scale;
        }
#pragma unroll
        for (int p = 0; p < PIX; p++) {
            int wx = wbase + p;
            float r = acc[p] + bv;
            if (BNSILU) {
                r = r * scale + shift;
                r = r / (1.f + expf(-r));   // silu
            }
            out[((size_t)(b * HH + h0) * WW + wx) * Cout + oc] = r;
        }
    }
}

// ---------------- deformable bilinear sample + depthwise-K einsum ----------------
// block: 256 threads = 4 pixels x 64 channels. Wave = 64 channels of one pixel:
// offset loads are wave-uniform broadcasts; channel gathers coalesced.
__global__ void dsample_k(const float* __restrict__ in, int Cin_tot, int ci_base,
                          const float* __restrict__ off, const float* __restrict__ dwT,
                          float* __restrict__ out, int k, int pad, int dil) {
    int t  = threadIdx.x;
    int c  = t & 63;
    int pl = t >> 6;
    int pix = blockIdx.x * 4 + pl;
    int wq = pix % WW;
    int r  = pix / WW;
    int h  = r % HH;
    int b  = r / HH;
    int K = k * k;
    const float* offp  = off + (size_t)pix * (2 * K);
    const float* ibase = in + (size_t)b * HH * WW * Cin_tot + ci_base + c;
    float acc = 0.f;
    int kk = 0;
    for (int ky = 0; ky < k; ky++) {
        float byk = (float)(h + ky * dil - pad);
        for (int kx = 0; kx < k; kx++, kk++) {
            float dy = offp[2 * kk];
            float dx = offp[2 * kk + 1];
            float py = byk + dy;
            float px = (float)(wq + kx * dil - pad) + dx;
            float y0f = floorf(py), x0f = floorf(px);
            float ty = py - y0f, tx = px - x0f;
            int iy0 = (int)y0f, ix0 = (int)x0f;
            float s = 0.f;
#pragma unroll
            for (int tap = 0; tap < 4; tap++) {
                int oy = iy0 + (tap >> 1);
                int ox = ix0 + (tap & 1);
                float wgt = ((tap >> 1) ? ty : 1.f - ty) * ((tap & 1) ? tx : 1.f - tx);
                if ((unsigned)oy < (unsigned)HH && (unsigned)ox < (unsigned)WW)
                    s = fmaf(wgt, ibase[((size_t)oy * WW + ox) * Cin_tot], s);
            }
            acc = fmaf(dwT[kk * 64 + c], s, acc);
        }
    }
    out[(size_t)pix * 64 + c] = acc;
}

// ---------------- 1x1 conv (64x64 matvec per pixel) + bias ----------------
__global__ void conv1x1_k(const float* __restrict__ in, const float* __restrict__ wT,
                          const float* __restrict__ bias, float* __restrict__ out) {
    int t  = threadIdx.x;
    int oc = t & 63;
    int pl = t >> 6;
    size_t pix = (size_t)blockIdx.x * 4 + pl;
    const float* ip = in + pix * 64;
    float acc = bias[oc];
#pragma unroll
    for (int ci = 0; ci < 64; ci++)
        acc = fmaf(ip[ci], wT[ci * 64 + oc], acc);
    out[pix * 64 + oc] = acc;
}

// ---------------- final: out(NCHW) = x + u*attn, NHWC->NCHW via padded LDS ----------------
__global__ void final_k(const float* __restrict__ x, const float* __restrict__ u,
                        const float* __restrict__ af, const float* __restrict__ bf,
                        float* __restrict__ out) {
    __shared__ float lu[16 * 130];
    __shared__ float lat[16 * 130];
    int t   = threadIdx.x;
    int blk = blockIdx.x;
    int wb = blk % 5;
    int r  = blk / 5;
    int h  = r % HH;
    int b  = r / HH;
    int w0 = wb * 16;
    size_t pixbase = (size_t)(b * HH + h) * WW + w0;
    for (int e = t; e < 16 * 128; e += 256) {
        int c = e & 127;
        int p = e >> 7;
        lu[p * 130 + c]  = u[(pixbase + p) * 128 + c];
        lat[p * 130 + c] = (c < 64) ? af[(pixbase + p) * 64 + c]
                                    : bf[(pixbase + p) * 64 + (c - 64)];
    }
    __syncthreads();
    for (int e = t; e < 16 * 128; e += 256) {
        int p = e & 15;
        int c = e >> 4;
        size_t gi = ((size_t)(b * CC + c) * HH + h) * WW + w0 + p;
        out[gi] = x[gi] + lu[p * 130 + c] * lat[p * 130 + c];
    }
}

extern "C" void kernel_launch(void* const* d_in, const int* in_sizes, int n_in,
                              void* d_out, int out_size, void* d_ws, size_t ws_size,
                              hipStream_t stream) {
    const float* x        = (const float*)d_in[0];
    const float* cv1_w    = (const float*)d_in[1];
    const float* bn_g     = (const float*)d_in[2];
    const float* bn_b     = (const float*)d_in[3];
    const float* bn_m     = (const float*)d_in[4];
    const float* bn_v     = (const float*)d_in[5];
    const float* a0_off_w = (const float*)d_in[6];
    const float* a0_off_b = (const float*)d_in[7];
    const float* a0_w     = (const float*)d_in[8];
    const float* a1_off_w = (const float*)d_in[9];
    const float* a1_off_b = (const float*)d_in[10];
    const float* a1_w     = (const float*)d_in[11];
    const float* b0_off_w = (const float*)d_in[12];
    const float* b0_off_b = (const float*)d_in[13];
    const float* b0_w     = (const float*)d_in[14];
    const float* b1_off_w = (const float*)d_in[15];
    const float* b1_off_b = (const float*)d_in[16];
    const float* b1_w     = (const float*)d_in[17];
    const float* conv1_w  = (const float*)d_in[18];
    const float* conv1_b  = (const float*)d_in[19];
    const float* conv2_w  = (const float*)d_in[20];
    const float* conv2_b  = (const float*)d_in[21];
    float* out = (float*)d_out;

    char* wsb = (char*)d_ws;
    size_t pos = 0;
    auto alloc = [&](size_t nf) -> float* {
        float* p = (float*)(wsb + pos);
        pos += ((nf * sizeof(float)) + 255) & ~(size_t)255;
        return p;
    };
    float* u_nhwc = alloc((size_t)NPIX * 128);   // post BN+SiLU, NHWC
    float* offbuf = alloc((size_t)NPIX * 98);    // reused by all 4 offset convs
    float* s0     = alloc((size_t)NPIX * 64);    // stage-1 deform out
    float* s1     = alloc((size_t)NPIX * 64);    // stage-2 deform out
    float* aF     = alloc((size_t)NPIX * 64);
    float* bF     = alloc((size_t)NPIX * 64);
    float* wt_cv1 = alloc(9 * 128 * 128);
    float* wt_a0  = alloc(9 * 64 * 64);
    float* wt_a1  = alloc(25 * 64 * 64);
    float* wt_b0  = alloc(25 * 64 * 64);
    float* wt_b1  = alloc(49 * 64 * 128);
    float* dwt_a0 = alloc(9 * 64);
    float* dwt_a1 = alloc(25 * 64);
    float* dwt_b0 = alloc(25 * 64);
    float* dwt_b1 = alloc(49 * 64);
    float* w1t    = alloc(64 * 64);
    float* w2t    = alloc(64 * 64);

    auto tw = [&](const float* src, float* dst, int O, int Opad, int I, int KK) {
        int n = KK * I * Opad;
        transpose_w_k<<<dim3((n + 255) / 256), dim3(256), 0, stream>>>(src, dst, O, Opad, I, KK);
    };
    tw(cv1_w,    wt_cv1, 128, 128, 128, 9);
    tw(a0_off_w, wt_a0,  18,  64,  64,  9);
    tw(a1_off_w, wt_a1,  50,  64,  64,  25);
    tw(b0_off_w, wt_b0,  50,  64,  64,  25);
    tw(b1_off_w, wt_b1,  98,  128, 64,  49);
    tw(a0_w,     dwt_a0, 64,  64,  9,   1);
    tw(a1_w,     dwt_a1, 64,  64,  25,  1);
    tw(b0_w,     dwt_b0, 64,  64,  25,  1);
    tw(b1_w,     dwt_b1, 64,  64,  49,  1);
    tw(conv1_w,  w1t,    64,  64,  64,  1);
    tw(conv2_w,  w2t,    64,  64,  64,  1);

    const int CONV_GRID = BB * HH * (WW / 20);   // 1280

    // main conv 3x3 (NCHW in) + BN + SiLU -> u_nhwc
    conv_k<10, 128, false, true><<<CONV_GRID, 256, 0, stream>>>(
        x, 128, 0, 128, wt_cv1, nullptr, 128, 3, 1, 1, bn_g, bn_b, bn_m, bn_v, u_nhwc);

    // ---- branch a (channels 0..63 of u) ----
    conv_k<5, 64, true, false><<<CONV_GRID, 256, 0, stream>>>(
        u_nhwc, 128, 0, 64, wt_a0, a0_off_b, 18, 3, 1, 1, nullptr, nullptr, nullptr, nullptr, offbuf);
    dsample_k<<<NPIX / 4, 256, 0, stream>>>(u_nhwc, 128, 0, offbuf, dwt_a0, s0, 3, 1, 1);
    conv_k<5, 64, true, false><<<CONV_GRID, 256, 0, stream>>>(
        s0, 64, 0, 64, wt_a1, a1_off_b, 50, 5, 6, 3, nullptr, nullptr, nullptr, nullptr, offbuf);
    dsample_k<<<NPIX / 4, 256, 0, stream>>>(s0, 64, 0, offbuf, dwt_a1, s1, 5, 6, 3);
    conv1x1_k<<<NPIX / 4, 256, 0, stream>>>(s1, w1t, conv1_b, aF);

    // ---- branch b (channels 64..127 of u) ----
    conv_k<5, 64, true, false><<<CONV_GRID, 256, 0, stream>>>(
        u_nhwc, 128, 64, 64, wt_b0, b0_off_b, 50, 5, 2, 1, nullptr, nullptr, nullptr, nullptr, offbuf);
    dsample_k<<<NPIX / 4, 256, 0, stream>>>(u_nhwc, 128, 64, offbuf, dwt_b0, s0, 5, 2, 1);
    conv_k<10, 128, true, false><<<CONV_GRID, 256, 0, stream>>>(
        s0, 64, 0, 64, wt_b1, b1_off_b, 98, 7, 9, 3, nullptr, nullptr, nullptr, nullptr, offbuf);
    dsample_k<<<NPIX / 4, 256, 0, stream>>>(s0, 64, 0, offbuf, dwt_b1, s1, 7, 9, 3);
    conv1x1_k<<<NPIX / 4, 256, 0, stream>>>(s1, w2t, conv2_b, bF);

    // ---- final: out = x + u * attn (NCHW) ----
    final_k<<<BB * HH * 5, 256, 0, stream>>>(x, u_nhwc, aF, bF, out);
}

// Round 2
// 549.881 us; speedup vs baseline: 6.9038x; 6.9038x over previous
//
#include <hip/hip_runtime.h>

#define HH 80
#define WW 80
#define BB 4
#define NPIX (BB*HH*WW)

typedef _Float16 f16;
typedef _Float16 f16x2 __attribute__((ext_vector_type(2)));
typedef _Float16 f16x8 __attribute__((ext_vector_type(8)));
typedef float    f32x4 __attribute__((ext_vector_type(4)));

// ---------------- f32 transpose for small weights: dst[t*I*Opad + i*Opad + o] = src[(o*I+i)*KK + t]
__global__ void transpose_w_k(const float* __restrict__ src, float* __restrict__ dst,
                              int O, int Opad, int I, int KK) {
    int n = KK * I * Opad;
    for (int idx = blockIdx.x * 256 + threadIdx.x; idx < n; idx += gridDim.x * 256) {
        int o = idx % Opad;
        int r = idx / Opad;
        int i = r % I;
        int t = r / I;
        dst[idx] = (o < O) ? src[((size_t)o * I + i) * KK + t] : 0.f;
    }
}

// ---------------- pack conv weights OIHW f32 -> MFMA B-frag layout f16 ----------------
// layout: [ks][ct][lane][8], element = W[n=ct*16+(l&15)][ci][tap], k-index kk=ks*32+(l>>4)*8+j
__global__ void pack_w_f16(const float* __restrict__ src, f16* __restrict__ dst,
                           int cout, int cin, int kk2, int nt_tot, int nk) {
    int total = nk * nt_tot * 512;
    for (int idx = blockIdx.x * 256 + threadIdx.x; idx < total; idx += gridDim.x * 256) {
        int j = idx & 7;
        int l = (idx >> 3) & 63;
        int rr = idx >> 9;
        int ct = rr % nt_tot;
        int ks = rr / nt_tot;
        int kkk = ks * 32 + (l >> 4) * 8 + j;
        int tap = kkk / cin;
        int ci  = kkk % cin;
        int n = ct * 16 + (l & 15);
        float v = (n < cout) ? src[((size_t)n * cin + ci) * kk2 + tap] : 0.f;
        dst[idx] = (f16)v;
    }
}

// ---------------- x (NCHW f32) -> xb (NHWC f16) via padded-LDS transpose ----------------
__global__ void xcvt_k(const float* __restrict__ x, f16* __restrict__ xb) {
    __shared__ float l[128 * 17];
    int t = threadIdx.x;
    int blk = blockIdx.x;           // B*H*5
    int wb = blk % 5;
    int r  = blk / 5;
    int h  = r % HH;
    int b  = r / HH;
    int w0 = wb * 16;
    size_t pixbase = (size_t)(b * HH + h) * WW + w0;
    for (int e = t; e < 2048; e += 256) {
        int c = e >> 4, p = e & 15;
        l[c * 17 + p] = x[((size_t)(b * 128 + c)) * (HH * WW) + h * WW + w0 + p];
    }
    __syncthreads();
    for (int e = t; e < 2048; e += 256) {
        int c = e & 127, p = e >> 7;
        xb[(pixbase + p) * 128 + c] = (f16)l[c * 17 + p];
    }
}

// ---------------- MFMA implicit-GEMM conv ----------------
// block = 256 thr = 4 waves; BM=64 pixels, BN=64 cols (blockIdx.y selects 64-col tile).
// wave w computes pixels [w*16, w*16+16) x 64 cols: 1 A-frag x 4 B-frags = 4 MFMA / K-step.
template<int K, int CIN, bool OUT_F16, bool BNSILU>
__global__ __launch_bounds__(256)
void mconv(const f16* __restrict__ in, int cin_tot, int ci_base,
           const f16* __restrict__ wp, int nt_tot,
           const float* __restrict__ bias,
           int cout, int out_stride, int pad, int dil,
           float* __restrict__ outf, f16* __restrict__ outh,
           const float* __restrict__ bn_g, const float* __restrict__ bn_b,
           const float* __restrict__ bn_m, const float* __restrict__ bn_v,
           const f16* __restrict__ zbuf) {
    constexpr int NK  = K * K * CIN / 32;   // K-steps
    constexpr int SPT = CIN / 32;           // K-steps per tap
    __shared__ f16 Ab[2][2048];             // 2 x 64px x 32k
    const int t    = threadIdx.x;
    const int lane = t & 63;
    const int wv   = t >> 6;
    const int blkpix = blockIdx.x * 64;
    const int ntb    = blockIdx.y * 4;

    // staging role: thread t loads 8 channels (16B) for pixel mm, LDS slot t&3.
    // channel-group permuted so the linear LDS write equals the swizzled layout.
    const int mm = t >> 2;
    const int gg = (t & 3) ^ ((mm >> 1) & 3);
    int pix  = blkpix + mm;
    int pb   = pix / (HH * WW);
    int prem = pix - pb * (HH * WW);
    int ph   = prem / WW;
    int pw   = prem - ph * WW;
    const f16* inb = in + (size_t)pb * (HH * WW) * cin_tot + ci_base;

    auto stage = [&](int ks, int buf) {
        int tap = ks / SPT;
        int ci0 = (ks - tap * SPT) * 32 + gg * 8;
        int ky = tap / K, kx = tap - ky * K;
        int y = ph + ky * dil - pad;
        int x = pw + kx * dil - pad;
        const f16* src = ((unsigned)y < (unsigned)HH && (unsigned)x < (unsigned)WW)
            ? inb + ((size_t)(y * WW + x)) * cin_tot + ci0
            : zbuf;
        __builtin_amdgcn_global_load_lds(
            (const __attribute__((address_space(1))) void*)src,
            (__attribute__((address_space(3))) void*)&Ab[buf][t * 8],
            16, 0, 0);
    };

    // A-frag read address (XOR slot swizzle -> uniform bank spread)
    const int ml   = wv * 16 + (lane & 15);
    const int koff = lane >> 4;
    const int aoff = ml * 32 + (koff ^ ((ml >> 1) & 3)) * 8;

    f32x4 acc0 = {0.f,0.f,0.f,0.f}, acc1 = acc0, acc2 = acc0, acc3 = acc0;

    stage(0, 0);
    __syncthreads();
    int cur = 0;
#pragma unroll 2
    for (int ks = 0; ks < NK; ks++) {
        if (ks + 1 < NK) stage(ks + 1, cur ^ 1);
        const f16x8* bp = (const f16x8*)wp + ((size_t)ks * nt_tot + ntb) * 64 + lane;
        f16x8 b0 = bp[0], b1 = bp[64], b2 = bp[128], b3 = bp[192];
        f16x8 a  = *(const f16x8*)&Ab[cur][aoff];
        acc0 = __builtin_amdgcn_mfma_f32_16x16x32_f16(a, b0, acc0, 0, 0, 0);
        acc1 = __builtin_amdgcn_mfma_f32_16x16x32_f16(a, b1, acc1, 0, 0, 0);
        acc2 = __builtin_amdgcn_mfma_f32_16x16x32_f16(a, b2, acc2, 0, 0, 0);
        acc3 = __builtin_amdgcn_mfma_f32_16x16x32_f16(a, b3, acc3, 0, 0, 0);
        __syncthreads();
        cur ^= 1;
    }

    // epilogue: C/D layout col=lane&15, row=(lane>>4)*4+reg
    const int nloc = lane & 15;
    const int prow = blkpix + wv * 16 + (lane >> 4) * 4;
    f32x4 accs[4] = {acc0, acc1, acc2, acc3};
#pragma unroll
    for (int ct = 0; ct < 4; ct++) {
        int n = (ntb + ct) * 16 + nloc;
        if (n >= cout) continue;
        float sc = 1.f, sh = 0.f, bv = 0.f;
        if (BNSILU) {
            sc = bn_g[n] / sqrtf(bn_v[n] + 1e-5f);
            sh = bn_b[n] - bn_m[n] * sc;
        } else if (bias) {
            bv = bias[n];
        }
#pragma unroll
        for (int r = 0; r < 4; r++) {
            float v = accs[ct][r] + bv;
            if (BNSILU) { v = v * sc + sh; v = v / (1.f + expf(-v)); }
            size_t o = (size_t)(prow + r) * out_stride + n;
            if (OUT_F16) outh[o] = (f16)v; else outf[o] = v;
        }
    }
}

// ---------------- deformable bilinear sample + depthwise-K einsum (2 ch / thread) ----------------
__global__ void dsample_k(const f16* __restrict__ in, int cin_tot, int ci_base,
                          const float* __restrict__ off, int off_stride,
                          const float* __restrict__ dwT,
                          f16* __restrict__ out, int k, int pad, int dil) {
    int t  = threadIdx.x;
    int c2 = (t & 31) * 2;
    int pl = t >> 5;                       // 8 pixels per block
    int pix = blockIdx.x * 8 + pl;
    int w = pix % WW;
    int r = pix / WW;
    int h = r % HH;
    int b = r / HH;
    const float* offp  = off + (size_t)pix * off_stride;
    const f16*   ibase = in + (size_t)b * (HH * WW) * cin_tot + ci_base + c2;
    float a0 = 0.f, a1 = 0.f;
    int kk = 0;
    for (int ky = 0; ky < k; ky++) {
        float byk = (float)(h + ky * dil - pad);
        for (int kx = 0; kx < k; kx++, kk++) {
            float2 d = *(const float2*)&offp[2 * kk];
            float py = byk + d.x;
            float px = (float)(w + kx * dil - pad) + d.y;
            float y0f = floorf(py), x0f = floorf(px);
            float ty = py - y0f, tx = px - x0f;
            int iy0 = (int)y0f, ix0 = (int)x0f;
            float s0 = 0.f, s1 = 0.f;
#pragma unroll
            for (int tap = 0; tap < 4; tap++) {
                int oy = iy0 + (tap >> 1);
                int ox = ix0 + (tap & 1);
                float wgt = ((tap >> 1) ? ty : 1.f - ty) * ((tap & 1) ? tx : 1.f - tx);
                if ((unsigned)oy < (unsigned)HH && (unsigned)ox < (unsigned)WW) {
                    f16x2 v = *(const f16x2*)&ibase[((size_t)(oy * WW + ox)) * cin_tot];
                    s0 = fmaf(wgt, (float)v.x, s0);
                    s1 = fmaf(wgt, (float)v.y, s1);
                }
            }
            float2 dw = *(const float2*)&dwT[kk * 64 + c2];
            a0 = fmaf(dw.x, s0, a0);
            a1 = fmaf(dw.y, s1, a1);
        }
    }
    f16x2 o2 = {(f16)a0, (f16)a1};
    *(f16x2*)&out[(size_t)pix * 64 + c2] = o2;
}

// ---------------- 1x1 conv (64x64 matvec per pixel) + bias, f16 in / f32 out ----------------
__global__ void conv1x1_k(const f16* __restrict__ in, const float* __restrict__ wT,
                          const float* __restrict__ bias, float* __restrict__ out) {
    int t  = threadIdx.x;
    int oc = t & 63;
    int pl = t >> 6;
    size_t pix = (size_t)blockIdx.x * 4 + pl;
    const f16* ip = in + pix * 64;
    float acc = bias[oc];
#pragma unroll
    for (int ci = 0; ci < 64; ci++)
        acc = fmaf((float)ip[ci], wT[ci * 64 + oc], acc);
    out[pix * 64 + oc] = acc;
}

// ---------------- final: out(NCHW) = x + u*attn ----------------
__global__ void final_k(const float* __restrict__ x, const f16* __restrict__ u,
                        const float* __restrict__ af, const float* __restrict__ bf,
                        float* __restrict__ out) {
    __shared__ float lu[16 * 130];
    __shared__ float lat[16 * 130];
    int t   = threadIdx.x;
    int blk = blockIdx.x;
    int wb = blk % 5;
    int r  = blk / 5;
    int h  = r % HH;
    int b  = r / HH;
    int w0 = wb * 16;
    size_t pixbase = (size_t)(b * HH + h) * WW + w0;
    for (int e = t; e < 16 * 128; e += 256) {
        int c = e & 127;
        int p = e >> 7;
        lu[p * 130 + c]  = (float)u[(pixbase + p) * 128 + c];
        lat[p * 130 + c] = (c < 64) ? af[(pixbase + p) * 64 + c]
                                    : bf[(pixbase + p) * 64 + (c - 64)];
    }
    __syncthreads();
    for (int e = t; e < 16 * 128; e += 256) {
        int p = e & 15;
        int c = e >> 4;
        size_t gi = ((size_t)(b * 128 + c) * HH + h) * WW + w0 + p;
        out[gi] = x[gi] + lu[p * 130 + c] * lat[p * 130 + c];
    }
}

extern "C" void kernel_launch(void* const* d_in, const int* in_sizes, int n_in,
                              void* d_out, int out_size, void* d_ws, size_t ws_size,
                              hipStream_t stream) {
    const float* x        = (const float*)d_in[0];
    const float* cv1_w    = (const float*)d_in[1];
    const float* bn_g     = (const float*)d_in[2];
    const float* bn_b     = (const float*)d_in[3];
    const float* bn_m     = (const float*)d_in[4];
    const float* bn_v     = (const float*)d_in[5];
    const float* a0_off_w = (const float*)d_in[6];
    const float* a0_off_b = (const float*)d_in[7];
    const float* a0_w     = (const float*)d_in[8];
    const float* a1_off_w = (const float*)d_in[9];
    const float* a1_off_b = (const float*)d_in[10];
    const float* a1_w     = (const float*)d_in[11];
    const float* b0_off_w = (const float*)d_in[12];
    const float* b0_off_b = (const float*)d_in[13];
    const float* b0_w     = (const float*)d_in[14];
    const float* b1_off_w = (const float*)d_in[15];
    const float* b1_off_b = (const float*)d_in[16];
    const float* b1_w     = (const float*)d_in[17];
    const float* conv1_w  = (const float*)d_in[18];
    const float* conv1_b  = (const float*)d_in[19];
    const float* conv2_w  = (const float*)d_in[20];
    const float* conv2_b  = (const float*)d_in[21];
    float* out = (float*)d_out;

    char* wsb = (char*)d_ws;
    size_t pos = 0;
    auto alloc = [&](size_t bytes) -> void* {
        void* p = (void*)(wsb + pos);
        pos += (bytes + 255) & ~(size_t)255;
        return p;
    };
    f16*   zbuf   = (f16*)  alloc(256);
    f16*   xb     = (f16*)  alloc((size_t)NPIX * 128 * 2);
    f16*   u      = (f16*)  alloc((size_t)NPIX * 128 * 2);
    f16*   s0     = (f16*)  alloc((size_t)NPIX * 64 * 2);
    f16*   s1     = (f16*)  alloc((size_t)NPIX * 64 * 2);
    float* offbuf = (float*)alloc((size_t)NPIX * 128 * 4);
    float* aF     = (float*)alloc((size_t)NPIX * 64 * 4);
    float* bF     = (float*)alloc((size_t)NPIX * 64 * 4);
    f16*   pcv1   = (f16*)  alloc((size_t)36 * 8 * 512 * 2);
    f16*   pa0    = (f16*)  alloc((size_t)18 * 4 * 512 * 2);
    f16*   pa1    = (f16*)  alloc((size_t)50 * 4 * 512 * 2);
    f16*   pb0    = (f16*)  alloc((size_t)50 * 4 * 512 * 2);
    f16*   pb1    = (f16*)  alloc((size_t)98 * 8 * 512 * 2);
    float* dwt_a0 = (float*)alloc(9  * 64 * 4);
    float* dwt_a1 = (float*)alloc(25 * 64 * 4);
    float* dwt_b0 = (float*)alloc(25 * 64 * 4);
    float* dwt_b1 = (float*)alloc(49 * 64 * 4);
    float* w1t    = (float*)alloc(64 * 64 * 4);
    float* w2t    = (float*)alloc(64 * 64 * 4);

    hipMemsetAsync(zbuf, 0, 256, stream);
    xcvt_k<<<dim3(BB * HH * 5), dim3(256), 0, stream>>>(x, xb);

    auto pk = [&](const float* src, f16* dst, int cout, int cin, int kk2, int nt, int nk) {
        int total = nk * nt * 512;
        int g = (total + 255) / 256; if (g > 1024) g = 1024;
        pack_w_f16<<<dim3(g), dim3(256), 0, stream>>>(src, dst, cout, cin, kk2, nt, nk);
    };
    pk(cv1_w,    pcv1, 128, 128, 9,  8, 36);
    pk(a0_off_w, pa0,  18,  64,  9,  4, 18);
    pk(a1_off_w, pa1,  50,  64,  25, 4, 50);
    pk(b0_off_w, pb0,  50,  64,  25, 4, 50);
    pk(b1_off_w, pb1,  98,  64,  49, 8, 98);

    auto tw = [&](const float* src, float* dst, int O, int Opad, int I, int KK) {
        int n = KK * I * Opad;
        transpose_w_k<<<dim3((n + 255) / 256), dim3(256), 0, stream>>>(src, dst, O, Opad, I, KK);
    };
    tw(a0_w,    dwt_a0, 64, 64, 1,  9);
    tw(a1_w,    dwt_a1, 64, 64, 1,  25);
    tw(b0_w,    dwt_b0, 64, 64, 1,  25);
    tw(b1_w,    dwt_b1, 64, 64, 1,  49);
    tw(conv1_w, w1t,    64, 64, 64, 1);
    tw(conv2_w, w2t,    64, 64, 64, 1);

    // main 3x3 conv + BN + SiLU -> u (f16 NHWC, stride 128)
    mconv<3, 128, true, true><<<dim3(400, 2), dim3(256), 0, stream>>>(
        xb, 128, 0, pcv1, 8, nullptr, 128, 128, 1, 1,
        nullptr, u, bn_g, bn_b, bn_m, bn_v, zbuf);

    // ---- branch a ----
    mconv<3, 64, false, false><<<dim3(400, 1), dim3(256), 0, stream>>>(
        u, 128, 0, pa0, 4, a0_off_b, 18, 64, 1, 1,
        offbuf, nullptr, nullptr, nullptr, nullptr, nullptr, zbuf);
    dsample_k<<<dim3(NPIX / 8), dim3(256), 0, stream>>>(u, 128, 0, offbuf, 64, dwt_a0, s0, 3, 1, 1);
    mconv<5, 64, false, false><<<dim3(400, 1), dim3(256), 0, stream>>>(
        s0, 64, 0, pa1, 4, a1_off_b, 50, 64, 6, 3,
        offbuf, nullptr, nullptr, nullptr, nullptr, nullptr, zbuf);
    dsample_k<<<dim3(NPIX / 8), dim3(256), 0, stream>>>(s0, 64, 0, offbuf, 64, dwt_a1, s1, 5, 6, 3);
    conv1x1_k<<<dim3(NPIX / 4), dim3(256), 0, stream>>>(s1, w1t, conv1_b, aF);

    // ---- branch b ----
    mconv<5, 64, false, false><<<dim3(400, 1), dim3(256), 0, stream>>>(
        u, 128, 64, pb0, 4, b0_off_b, 50, 64, 2, 1,
        offbuf, nullptr, nullptr, nullptr, nullptr, nullptr, zbuf);
    dsample_k<<<dim3(NPIX / 8), dim3(256), 0, stream>>>(u, 128, 64, offbuf, 64, dwt_b0, s0, 5, 2, 1);
    mconv<7, 64, false, false><<<dim3(400, 2), dim3(256), 0, stream>>>(
        s0, 64, 0, pb1, 8, b1_off_b, 98, 128, 9, 3,
        offbuf, nullptr, nullptr, nullptr, nullptr, nullptr, zbuf);
    dsample_k<<<dim3(NPIX / 8), dim3(256), 0, stream>>>(s0, 64, 0, offbuf, 128, dwt_b1, s1, 7, 9, 3);
    conv1x1_k<<<dim3(NPIX / 4), dim3(256), 0, stream>>>(s1, w2t, conv2_b, bF);

    // ---- final ----
    final_k<<<dim3(BB * HH * 5), dim3(256), 0, stream>>>(x, u, aF, bF, out);
}

// Round 3
// 328.184 us; speedup vs baseline: 11.5675x; 1.6755x over previous
//
#include <hip/hip_runtime.h>

#define HH 80
#define WW 80
#define BB 4
#define NPIX (BB*HH*WW)

typedef _Float16 f16;
typedef _Float16 f16x2 __attribute__((ext_vector_type(2)));
typedef _Float16 f16x8 __attribute__((ext_vector_type(8)));
typedef float    f32x4 __attribute__((ext_vector_type(4)));
typedef unsigned int uint;
typedef unsigned short ushort;

__device__ inline uint packsplat(float w) {
    f16 h = (f16)w;
    ushort u = __builtin_bit_cast(ushort, h);
    return (uint)u * 0x10001u;
}
__device__ inline f16x8 splat8(uint u) {
    uint4 q = {u, u, u, u};
    return __builtin_bit_cast(f16x8, q);
}

// ---------------- f32 transpose for small weights: dst[t*I*Opad + i*Opad + o] = src[(o*I+i)*KK + t]
__global__ void transpose_w_k(const float* __restrict__ src, float* __restrict__ dst,
                              int O, int Opad, int I, int KK) {
    int n = KK * I * Opad;
    for (int idx = blockIdx.x * 256 + threadIdx.x; idx < n; idx += gridDim.x * 256) {
        int o = idx % Opad;
        int r = idx / Opad;
        int i = r % I;
        int t = r / I;
        dst[idx] = (o < O) ? src[((size_t)o * I + i) * KK + t] : 0.f;
    }
}

// ---------------- pack conv weights OIHW f32 -> MFMA B-frag layout f16 ----------------
__global__ void pack_w_f16(const float* __restrict__ src, f16* __restrict__ dst,
                           int cout, int cin, int kk2, int nt_tot, int nk) {
    int total = nk * nt_tot * 512;
    for (int idx = blockIdx.x * 256 + threadIdx.x; idx < total; idx += gridDim.x * 256) {
        int j = idx & 7;
        int l = (idx >> 3) & 63;
        int rr = idx >> 9;
        int ct = rr % nt_tot;
        int ks = rr / nt_tot;
        int kkk = ks * 32 + (l >> 4) * 8 + j;
        int tap = kkk / cin;
        int ci  = kkk % cin;
        int n = ct * 16 + (l & 15);
        float v = (n < cout) ? src[((size_t)n * cin + ci) * kk2 + tap] : 0.f;
        dst[idx] = (f16)v;
    }
}

// ---------------- x (NCHW f32) -> xb (NHWC f16) via padded-LDS transpose ----------------
__global__ void xcvt_k(const float* __restrict__ x, f16* __restrict__ xb) {
    __shared__ float l[128 * 17];
    int t = threadIdx.x;
    int blk = blockIdx.x;           // B*H*5
    int wb = blk % 5;
    int r  = blk / 5;
    int h  = r % HH;
    int b  = r / HH;
    int w0 = wb * 16;
    size_t pixbase = (size_t)(b * HH + h) * WW + w0;
    for (int e = t; e < 2048; e += 256) {
        int c = e >> 4, p = e & 15;
        l[c * 17 + p] = x[((size_t)(b * 128 + c)) * (HH * WW) + h * WW + w0 + p];
    }
    __syncthreads();
    for (int e = t; e < 2048; e += 256) {
        int c = e & 127, p = e >> 7;
        xb[(pixbase + p) * 128 + c] = (f16)l[c * 17 + p];
    }
}

// ---------------- MFMA implicit-GEMM conv ----------------
template<int K, int CIN, bool OUT_F16, bool BNSILU>
__global__ __launch_bounds__(256)
void mconv(const f16* __restrict__ in, int cin_tot, int ci_base,
           const f16* __restrict__ wp, int nt_tot,
           const float* __restrict__ bias,
           int cout, int out_stride, int pad, int dil,
           float* __restrict__ outf, f16* __restrict__ outh,
           const float* __restrict__ bn_g, const float* __restrict__ bn_b,
           const float* __restrict__ bn_m, const float* __restrict__ bn_v,
           const f16* __restrict__ zbuf) {
    constexpr int NK  = K * K * CIN / 32;   // K-steps
    constexpr int SPT = CIN / 32;           // K-steps per tap
    __shared__ f16 Ab[2][2048];             // 2 x 64px x 32k
    const int t    = threadIdx.x;
    const int lane = t & 63;
    const int wv   = t >> 6;
    const int blkpix = blockIdx.x * 64;
    const int ntb    = blockIdx.y * 4;

    const int mm = t >> 2;
    const int gg = (t & 3) ^ ((mm >> 1) & 3);
    int pix  = blkpix + mm;
    int pb   = pix / (HH * WW);
    int prem = pix - pb * (HH * WW);
    int ph   = prem / WW;
    int pw   = prem - ph * WW;
    const f16* inb = in + (size_t)pb * (HH * WW) * cin_tot + ci_base;

    auto stage = [&](int ks, int buf) {
        int tap = ks / SPT;
        int ci0 = (ks - tap * SPT) * 32 + gg * 8;
        int ky = tap / K, kx = tap - ky * K;
        int y = ph + ky * dil - pad;
        int x = pw + kx * dil - pad;
        const f16* src = ((unsigned)y < (unsigned)HH && (unsigned)x < (unsigned)WW)
            ? inb + ((size_t)(y * WW + x)) * cin_tot + ci0
            : zbuf;
        __builtin_amdgcn_global_load_lds(
            (const __attribute__((address_space(1))) void*)src,
            (__attribute__((address_space(3))) void*)&Ab[buf][t * 8],
            16, 0, 0);
    };

    const int ml   = wv * 16 + (lane & 15);
    const int koff = lane >> 4;
    const int aoff = ml * 32 + (koff ^ ((ml >> 1) & 3)) * 8;

    f32x4 acc0 = {0.f,0.f,0.f,0.f}, acc1 = acc0, acc2 = acc0, acc3 = acc0;

    stage(0, 0);
    __syncthreads();
    int cur = 0;
#pragma unroll 2
    for (int ks = 0; ks < NK; ks++) {
        if (ks + 1 < NK) stage(ks + 1, cur ^ 1);
        const f16x8* bp = (const f16x8*)wp + ((size_t)ks * nt_tot + ntb) * 64 + lane;
        f16x8 b0 = bp[0], b1 = bp[64], b2 = bp[128], b3 = bp[192];
        f16x8 a  = *(const f16x8*)&Ab[cur][aoff];
        acc0 = __builtin_amdgcn_mfma_f32_16x16x32_f16(a, b0, acc0, 0, 0, 0);
        acc1 = __builtin_amdgcn_mfma_f32_16x16x32_f16(a, b1, acc1, 0, 0, 0);
        acc2 = __builtin_amdgcn_mfma_f32_16x16x32_f16(a, b2, acc2, 0, 0, 0);
        acc3 = __builtin_amdgcn_mfma_f32_16x16x32_f16(a, b3, acc3, 0, 0, 0);
        __syncthreads();
        cur ^= 1;
    }

    const int nloc = lane & 15;
    const int prow = blkpix + wv * 16 + (lane >> 4) * 4;
    f32x4 accs[4] = {acc0, acc1, acc2, acc3};
#pragma unroll
    for (int ct = 0; ct < 4; ct++) {
        int n = (ntb + ct) * 16 + nloc;
        if (n >= cout) continue;
        float sc = 1.f, sh = 0.f, bv = 0.f;
        if (BNSILU) {
            sc = bn_g[n] / sqrtf(bn_v[n] + 1e-5f);
            sh = bn_b[n] - bn_m[n] * sc;
        } else if (bias) {
            bv = bias[n];
        }
#pragma unroll
        for (int r = 0; r < 4; r++) {
            float v = accs[ct][r] + bv;
            if (BNSILU) { v = v * sc + sh; v = v / (1.f + expf(-v)); }
            size_t o = (size_t)(prow + r) * out_stride + n;
            if (OUT_F16) outh[o] = (f16)v; else outf[o] = v;
        }
    }
}

// ---------------- deformable sample, two-phase ----------------
// Phase 1: per (pixel, tap) compute 4 corner byte-offsets (clamped, batch-folded)
//          and 4 bilinear weights (validity folded in, packed f16x2-splat) -> LDS.
// Phase 2: 32 pixels x 8 lanes x f16x8 channels, branch-free gather+blend,
//          f32 tap accumulation with f32 depthwise weights.
template<int KS, int PAD, int DIL>
__global__ __launch_bounds__(256)
void dsample2_k(const f16* __restrict__ in, int cin_tot, int csh, int ci_base,
                const float* __restrict__ off, int off_stride,
                const float* __restrict__ dwT, f16* __restrict__ out) {
    constexpr int K = KS * KS;
    __shared__ uint4 wts[32 * K];
    __shared__ int4  ofs[32 * K];
    const int t   = threadIdx.x;
    const int blk = blockIdx.x;

    for (int e = t; e < 32 * K; e += 256) {
        int p  = e / K;
        int kk = e - p * K;
        int pix = blk * 32 + p;
        int b   = pix / (HH * WW);
        int rem = pix - b * (HH * WW);
        int h   = rem / WW;
        int w   = rem - h * WW;
        int ky = kk / KS, kx = kk - ky * KS;
        float2 d = *(const float2*)&off[(size_t)pix * off_stride + 2 * kk];
        float py = (float)(h + ky * DIL - PAD) + d.x;
        float px = (float)(w + kx * DIL - PAD) + d.y;
        float y0f = floorf(py), x0f = floorf(px);
        float ty = py - y0f, tx = px - x0f;
        int iy0 = (int)y0f, ix0 = (int)x0f;
        bool vy0 = (unsigned)iy0 < (unsigned)HH;
        bool vy1 = (unsigned)(iy0 + 1) < (unsigned)HH;
        bool vx0 = (unsigned)ix0 < (unsigned)WW;
        bool vx1 = (unsigned)(ix0 + 1) < (unsigned)WW;
        int cy0 = min(max(iy0, 0), HH - 1), cy1 = min(max(iy0 + 1, 0), HH - 1);
        int cx0 = min(max(ix0, 0), WW - 1), cx1 = min(max(ix0 + 1, 0), WW - 1);
        float wy0 = 1.f - ty, wx0 = 1.f - tx;
        uint4 wq;
        wq.x = packsplat(wy0 * wx0 * ((vy0 && vx0) ? 1.f : 0.f));
        wq.y = packsplat(wy0 * tx  * ((vy0 && vx1) ? 1.f : 0.f));
        wq.z = packsplat(ty  * wx0 * ((vy1 && vx0) ? 1.f : 0.f));
        wq.w = packsplat(ty  * tx  * ((vy1 && vx1) ? 1.f : 0.f));
        int base = b * (HH * WW);
        int4 oq;
        oq.x = (base + cy0 * WW + cx0) << csh;
        oq.y = (base + cy0 * WW + cx1) << csh;
        oq.z = (base + cy1 * WW + cx0) << csh;
        oq.w = (base + cy1 * WW + cx1) << csh;
        wts[e] = wq;
        ofs[e] = oq;
    }
    __syncthreads();

    const int li  = t & 7;
    const int p   = t >> 3;
    const int ch0 = li * 8;
    const int pix = blk * 32 + p;
    const char* ibase = (const char*)(in + ci_base) + ch0 * 2;

    float acc[8];
#pragma unroll
    for (int j = 0; j < 8; j++) acc[j] = 0.f;

#pragma unroll 2
    for (int kk = 0; kk < K; kk++) {
        uint4 wq = wts[p * K + kk];
        int4  oq = ofs[p * K + kk];
        f16x8 c00 = *(const f16x8*)(ibase + oq.x);
        f16x8 c01 = *(const f16x8*)(ibase + oq.y);
        f16x8 c10 = *(const f16x8*)(ibase + oq.z);
        f16x8 c11 = *(const f16x8*)(ibase + oq.w);
        f16x8 s = c00 * splat8(wq.x);
        s = c01 * splat8(wq.y) + s;
        s = c10 * splat8(wq.z) + s;
        s = c11 * splat8(wq.w) + s;
        float4 d0 = *(const float4*)(dwT + kk * 64 + ch0);
        float4 d1 = *(const float4*)(dwT + kk * 64 + ch0 + 4);
        acc[0] = fmaf(d0.x, (float)s[0], acc[0]);
        acc[1] = fmaf(d0.y, (float)s[1], acc[1]);
        acc[2] = fmaf(d0.z, (float)s[2], acc[2]);
        acc[3] = fmaf(d0.w, (float)s[3], acc[3]);
        acc[4] = fmaf(d1.x, (float)s[4], acc[4]);
        acc[5] = fmaf(d1.y, (float)s[5], acc[5]);
        acc[6] = fmaf(d1.z, (float)s[6], acc[6]);
        acc[7] = fmaf(d1.w, (float)s[7], acc[7]);
    }

    f16x8 o;
#pragma unroll
    for (int j = 0; j < 8; j++) o[j] = (f16)acc[j];
    *(f16x8*)&out[(size_t)pix * 64 + ch0] = o;
}

// ---------------- final: out(NCHW) = x + u*attn ----------------
__global__ void final_k(const float* __restrict__ x, const f16* __restrict__ u,
                        const float* __restrict__ af, const float* __restrict__ bf,
                        float* __restrict__ out) {
    __shared__ float lu[16 * 130];
    __shared__ float lat[16 * 130];
    int t   = threadIdx.x;
    int blk = blockIdx.x;
    int wb = blk % 5;
    int r  = blk / 5;
    int h  = r % HH;
    int b  = r / HH;
    int w0 = wb * 16;
    size_t pixbase = (size_t)(b * HH + h) * WW + w0;
    for (int e = t; e < 16 * 128; e += 256) {
        int c = e & 127;
        int p = e >> 7;
        lu[p * 130 + c]  = (float)u[(pixbase + p) * 128 + c];
        lat[p * 130 + c] = (c < 64) ? af[(pixbase + p) * 64 + c]
                                    : bf[(pixbase + p) * 64 + (c - 64)];
    }
    __syncthreads();
    for (int e = t; e < 16 * 128; e += 256) {
        int p = e & 15;
        int c = e >> 4;
        size_t gi = ((size_t)(b * 128 + c) * HH + h) * WW + w0 + p;
        out[gi] = x[gi] + lu[p * 130 + c] * lat[p * 130 + c];
    }
}

extern "C" void kernel_launch(void* const* d_in, const int* in_sizes, int n_in,
                              void* d_out, int out_size, void* d_ws, size_t ws_size,
                              hipStream_t stream) {
    const float* x        = (const float*)d_in[0];
    const float* cv1_w    = (const float*)d_in[1];
    const float* bn_g     = (const float*)d_in[2];
    const float* bn_b     = (const float*)d_in[3];
    const float* bn_m     = (const float*)d_in[4];
    const float* bn_v     = (const float*)d_in[5];
    const float* a0_off_w = (const float*)d_in[6];
    const float* a0_off_b = (const float*)d_in[7];
    const float* a0_w     = (const float*)d_in[8];
    const float* a1_off_w = (const float*)d_in[9];
    const float* a1_off_b = (const float*)d_in[10];
    const float* a1_w     = (const float*)d_in[11];
    const float* b0_off_w = (const float*)d_in[12];
    const float* b0_off_b = (const float*)d_in[13];
    const float* b0_w     = (const float*)d_in[14];
    const float* b1_off_w = (const float*)d_in[15];
    const float* b1_off_b = (const float*)d_in[16];
    const float* b1_w     = (const float*)d_in[17];
    const float* conv1_w  = (const float*)d_in[18];
    const float* conv1_b  = (const float*)d_in[19];
    const float* conv2_w  = (const float*)d_in[20];
    const float* conv2_b  = (const float*)d_in[21];
    float* out = (float*)d_out;

    char* wsb = (char*)d_ws;
    size_t pos = 0;
    auto alloc = [&](size_t bytes) -> void* {
        void* p = (void*)(wsb + pos);
        pos += (bytes + 255) & ~(size_t)255;
        return p;
    };
    f16*   zbuf   = (f16*)  alloc(256);
    f16*   xb     = (f16*)  alloc((size_t)NPIX * 128 * 2);
    f16*   u      = (f16*)  alloc((size_t)NPIX * 128 * 2);
    f16*   s0     = (f16*)  alloc((size_t)NPIX * 64 * 2);
    f16*   s1     = (f16*)  alloc((size_t)NPIX * 64 * 2);
    float* offbuf = (float*)alloc((size_t)NPIX * 128 * 4);
    float* aF     = (float*)alloc((size_t)NPIX * 64 * 4);
    float* bF     = (float*)alloc((size_t)NPIX * 64 * 4);
    f16*   pcv1   = (f16*)  alloc((size_t)36 * 8 * 512 * 2);
    f16*   pa0    = (f16*)  alloc((size_t)18 * 4 * 512 * 2);
    f16*   pa1    = (f16*)  alloc((size_t)50 * 4 * 512 * 2);
    f16*   pb0    = (f16*)  alloc((size_t)50 * 4 * 512 * 2);
    f16*   pb1    = (f16*)  alloc((size_t)98 * 8 * 512 * 2);
    f16*   pc1    = (f16*)  alloc((size_t)2  * 4 * 512 * 2);
    f16*   pc2    = (f16*)  alloc((size_t)2  * 4 * 512 * 2);
    float* dwt_a0 = (float*)alloc(9  * 64 * 4);
    float* dwt_a1 = (float*)alloc(25 * 64 * 4);
    float* dwt_b0 = (float*)alloc(25 * 64 * 4);
    float* dwt_b1 = (float*)alloc(49 * 64 * 4);

    hipMemsetAsync(zbuf, 0, 256, stream);
    xcvt_k<<<dim3(BB * HH * 5), dim3(256), 0, stream>>>(x, xb);

    auto pk = [&](const float* src, f16* dst, int cout, int cin, int kk2, int nt, int nk) {
        int total = nk * nt * 512;
        int g = (total + 255) / 256; if (g > 1024) g = 1024;
        pack_w_f16<<<dim3(g), dim3(256), 0, stream>>>(src, dst, cout, cin, kk2, nt, nk);
    };
    pk(cv1_w,    pcv1, 128, 128, 9,  8, 36);
    pk(a0_off_w, pa0,  18,  64,  9,  4, 18);
    pk(a1_off_w, pa1,  50,  64,  25, 4, 50);
    pk(b0_off_w, pb0,  50,  64,  25, 4, 50);
    pk(b1_off_w, pb1,  98,  64,  49, 8, 98);
    pk(conv1_w,  pc1,  64,  64,  1,  4, 2);
    pk(conv2_w,  pc2,  64,  64,  1,  4, 2);

    auto tw = [&](const float* src, float* dst, int O, int Opad, int I, int KK) {
        int n = KK * I * Opad;
        transpose_w_k<<<dim3((n + 255) / 256), dim3(256), 0, stream>>>(src, dst, O, Opad, I, KK);
    };
    tw(a0_w, dwt_a0, 64, 64, 1, 9);
    tw(a1_w, dwt_a1, 64, 64, 1, 25);
    tw(b0_w, dwt_b0, 64, 64, 1, 25);
    tw(b1_w, dwt_b1, 64, 64, 1, 49);

    // main 3x3 conv + BN + SiLU -> u (f16 NHWC, stride 128)
    mconv<3, 128, true, true><<<dim3(400, 2), dim3(256), 0, stream>>>(
        xb, 128, 0, pcv1, 8, nullptr, 128, 128, 1, 1,
        nullptr, u, bn_g, bn_b, bn_m, bn_v, zbuf);

    // ---- branch a ----
    mconv<3, 64, false, false><<<dim3(400, 1), dim3(256), 0, stream>>>(
        u, 128, 0, pa0, 4, a0_off_b, 18, 64, 1, 1,
        offbuf, nullptr, nullptr, nullptr, nullptr, nullptr, zbuf);
    dsample2_k<3, 1, 1><<<dim3(NPIX / 32), dim3(256), 0, stream>>>(
        u, 128, 8, 0, offbuf, 64, dwt_a0, s0);
    mconv<5, 64, false, false><<<dim3(400, 1), dim3(256), 0, stream>>>(
        s0, 64, 0, pa1, 4, a1_off_b, 50, 64, 6, 3,
        offbuf, nullptr, nullptr, nullptr, nullptr, nullptr, zbuf);
    dsample2_k<5, 6, 3><<<dim3(NPIX / 32), dim3(256), 0, stream>>>(
        s0, 64, 7, 0, offbuf, 64, dwt_a1, s1);
    mconv<1, 64, false, false><<<dim3(400, 1), dim3(256), 0, stream>>>(
        s1, 64, 0, pc1, 4, conv1_b, 64, 64, 0, 1,
        aF, nullptr, nullptr, nullptr, nullptr, nullptr, zbuf);

    // ---- branch b ----
    mconv<5, 64, false, false><<<dim3(400, 1), dim3(256), 0, stream>>>(
        u, 128, 64, pb0, 4, b0_off_b, 50, 64, 2, 1,
        offbuf, nullptr, nullptr, nullptr, nullptr, nullptr, zbuf);
    dsample2_k<5, 2, 1><<<dim3(NPIX / 32), dim3(256), 0, stream>>>(
        u, 128, 8, 64, offbuf, 64, dwt_b0, s0);
    mconv<7, 64, false, false><<<dim3(400, 2), dim3(256), 0, stream>>>(
        s0, 64, 0, pb1, 8, b1_off_b, 98, 128, 9, 3,
        offbuf, nullptr, nullptr, nullptr, nullptr, nullptr, zbuf);
    dsample2_k<7, 9, 3><<<dim3(NPIX / 32), dim3(256), 0, stream>>>(
        s0, 64, 7, 0, offbuf, 128, dwt_b1, s1);
    mconv<1, 64, false, false><<<dim3(400, 1), dim3(256), 0, stream>>>(
        s1, 64, 0, pc2, 4, conv2_b, 64, 64, 0, 1,
        bF, nullptr, nullptr, nullptr, nullptr, nullptr, zbuf);

    // ---- final ----
    final_k<<<dim3(BB * HH * 5), dim3(256), 0, stream>>>(x, u, aF, bF, out);
}

// Round 4
// 314.362 us; speedup vs baseline: 12.0761x; 1.0440x over previous
//
#include <hip/hip_runtime.h>

#define HH 80
#define WW 80
#define BB 4
#define NPIX (BB*HH*WW)

typedef _Float16 f16;
typedef _Float16 f16x8 __attribute__((ext_vector_type(8)));
typedef float    f32x4 __attribute__((ext_vector_type(4)));
typedef unsigned int uint;
typedef unsigned short ushort;

__device__ inline f16x8 splat8(uint u) {
    uint4 q = {u, u, u, u};
    return __builtin_bit_cast(f16x8, q);
}
__device__ inline ushort h_bits(float w) {
    f16 h = (f16)w;
    return __builtin_bit_cast(ushort, h);
}

// ---------------- f32 transpose for small weights ----------------
__global__ void transpose_w_k(const float* __restrict__ src, float* __restrict__ dst,
                              int O, int Opad, int I, int KK) {
    int n = KK * I * Opad;
    for (int idx = blockIdx.x * 256 + threadIdx.x; idx < n; idx += gridDim.x * 256) {
        int o = idx % Opad;
        int r = idx / Opad;
        int i = r % I;
        int t = r / I;
        dst[idx] = (o < O) ? src[((size_t)o * I + i) * KK + t] : 0.f;
    }
}

// ---------------- pack conv weights OIHW f32 -> MFMA B-frag layout f16 ----------------
// [ks][ct][lane][8]: element = W[n=ct*16+(l&15)][ci][tap], k = ks*32+(l>>4)*8+j
__global__ void pack_w_f16(const float* __restrict__ src, f16* __restrict__ dst,
                           int cout, int cin, int kk2, int nt_tot, int nk) {
    int total = nk * nt_tot * 512;
    for (int idx = blockIdx.x * 256 + threadIdx.x; idx < total; idx += gridDim.x * 256) {
        int j = idx & 7;
        int l = (idx >> 3) & 63;
        int rr = idx >> 9;
        int ct = rr % nt_tot;
        int ks = rr / nt_tot;
        int kkk = ks * 32 + (l >> 4) * 8 + j;
        int tap = kkk / cin;
        int ci  = kkk % cin;
        int n = ct * 16 + (l & 15);
        float v = (n < cout) ? src[((size_t)n * cin + ci) * kk2 + tap] : 0.f;
        dst[idx] = (f16)v;
    }
}

// ---------------- x (NCHW f32) -> xb (NHWC f16) ----------------
__global__ void xcvt_k(const float* __restrict__ x, f16* __restrict__ xb) {
    __shared__ float l[128 * 17];
    int t = threadIdx.x;
    int blk = blockIdx.x;
    int wb = blk % 5;
    int r  = blk / 5;
    int h  = r % HH;
    int b  = r / HH;
    int w0 = wb * 16;
    size_t pixbase = (size_t)(b * HH + h) * WW + w0;
    for (int e = t; e < 2048; e += 256) {
        int c = e >> 4, p = e & 15;
        l[c * 17 + p] = x[((size_t)(b * 128 + c)) * (HH * WW) + h * WW + w0 + p];
    }
    __syncthreads();
    for (int e = t; e < 2048; e += 256) {
        int c = e & 127, p = e >> 7;
        xb[(pixbase + p) * 128 + c] = (f16)l[c * 17 + p];
    }
}

// ---------------- MFMA implicit-GEMM conv, barrier-free, A direct to VGPR ----------------
struct MArgs {
    const f16* in; const f16* wp; const float* bias;
    float* outf; f16* outh;
    const float* bn_g; const float* bn_b; const float* bn_m; const float* bn_v;
    const f16* zbuf;
    int cin_tot, ci_base, nt_tot, cout, out_stride, pad, dil;
};

template<int K, int CIN, bool OUT_F16, bool BNSILU>
__device__ __forceinline__ void mconv_body(int bx, int by, const MArgs A) {
    constexpr int SPT = CIN / 32;
    const int t    = threadIdx.x;
    const int lane = t & 63;
    const int wv   = t >> 6;
    const int blkpix = bx * 64;
    const int ntb    = by * 4;

    // A-frag lane mapping: pixel row = wv*16 + (lane&15), k-chunk = (lane>>4)*8
    const int ml = wv * 16 + (lane & 15);
    int pix  = blkpix + ml;
    int pb   = pix / (HH * WW);
    int prem = pix - pb * (HH * WW);
    int ph   = prem / WW;
    int pw   = prem - ph * WW;
    const f16* inb = A.in + (size_t)pb * (HH * WW) * A.cin_tot + A.ci_base + (lane >> 4) * 8;
    const f16* wB  = A.wp + (size_t)ntb * 512 + lane * 8;
    const int ntstep = A.nt_tot * 512;

    f32x4 acc0 = {0.f,0.f,0.f,0.f}, acc1 = acc0, acc2 = acc0, acc3 = acc0;

    for (int ky = 0; ky < K; ky++) {
        int y = ph + ky * A.dil - A.pad;
        bool vy = (unsigned)y < (unsigned)HH;
        const f16* rowp = inb + (ptrdiff_t)y * WW * A.cin_tot;
        for (int kx = 0; kx < K; kx++) {
            int x = pw + kx * A.dil - A.pad;
            bool v = vy && ((unsigned)x < (unsigned)WW);
            const f16* ap = v ? rowp + (ptrdiff_t)x * A.cin_tot : A.zbuf;
#pragma unroll
            for (int s = 0; s < SPT; s++) {
                f16x8 a = *(const f16x8*)(ap + s * 32);
                const f16x8* bp = (const f16x8*)wB;
                f16x8 b0 = bp[0], b1 = bp[64], b2 = bp[128], b3 = bp[192];
                acc0 = __builtin_amdgcn_mfma_f32_16x16x32_f16(a, b0, acc0, 0, 0, 0);
                acc1 = __builtin_amdgcn_mfma_f32_16x16x32_f16(a, b1, acc1, 0, 0, 0);
                acc2 = __builtin_amdgcn_mfma_f32_16x16x32_f16(a, b2, acc2, 0, 0, 0);
                acc3 = __builtin_amdgcn_mfma_f32_16x16x32_f16(a, b3, acc3, 0, 0, 0);
                wB += ntstep;
            }
        }
    }

    const int nloc = lane & 15;
    const int prow = blkpix + wv * 16 + (lane >> 4) * 4;
    f32x4 accs[4] = {acc0, acc1, acc2, acc3};
#pragma unroll
    for (int ct = 0; ct < 4; ct++) {
        int n = (ntb + ct) * 16 + nloc;
        if (n >= A.cout) continue;
        float sc = 1.f, sh = 0.f, bv = 0.f;
        if (BNSILU) {
            sc = A.bn_g[n] / sqrtf(A.bn_v[n] + 1e-5f);
            sh = A.bn_b[n] - A.bn_m[n] * sc;
        } else if (A.bias) {
            bv = A.bias[n];
        }
#pragma unroll
        for (int r = 0; r < 4; r++) {
            float vv = accs[ct][r] + bv;
            if (BNSILU) { vv = vv * sc + sh; vv = vv / (1.f + expf(-vv)); }
            size_t o = (size_t)(prow + r) * A.out_stride + n;
            if (OUT_F16) A.outh[o] = (f16)vv; else A.outf[o] = vv;
        }
    }
}

__global__ __launch_bounds__(256) void mconv_main_k(MArgs A) {
    mconv_body<3, 128, true, true>(blockIdx.x % 400, blockIdx.x / 400, A);
}

template<int K1, int C1, int K2, int C2>
__global__ __launch_bounds__(256) void mconv_pair_k(MArgs A1, int nblk1, MArgs A2) {
    int b = blockIdx.x;
    if (b < nblk1) {
        mconv_body<K1, C1, false, false>(b % 400, b / 400, A1);
    } else {
        int bb = b - nblk1;
        mconv_body<K2, C2, false, false>(bb % 400, bb / 400, A2);
    }
}

// ---------------- deformable sample, two-phase, 16B LDS entries ----------------
struct DArgs {
    const f16* in; const float* off; const float* dwT; f16* out;
    int csh, ci_base, off_stride;
};
struct alignas(16) DEnt { int o00; short dx1, dy1; uint w01, w23; };

template<int KS, int PAD, int DIL>
__device__ __forceinline__ void dsample_body(int blk, char* ldsraw, const DArgs A) {
    constexpr int K = KS * KS;
    DEnt* ent = (DEnt*)ldsraw;
    const int t = threadIdx.x;

    for (int e = t; e < 32 * K; e += 256) {
        int p  = e / K;
        int kk = e - p * K;
        int pix = blk * 32 + p;
        int b   = pix / (HH * WW);
        int rem = pix - b * (HH * WW);
        int h   = rem / WW;
        int w   = rem - h * WW;
        int ky = kk / KS, kx = kk - ky * KS;
        float2 d = *(const float2*)&A.off[(size_t)pix * A.off_stride + 2 * kk];
        float py = (float)(h + ky * DIL - PAD) + d.x;
        float px = (float)(w + kx * DIL - PAD) + d.y;
        float y0f = floorf(py), x0f = floorf(px);
        float ty = py - y0f, tx = px - x0f;
        int iy0 = (int)y0f, ix0 = (int)x0f;
        bool vy0 = (unsigned)iy0 < (unsigned)HH;
        bool vy1 = (unsigned)(iy0 + 1) < (unsigned)HH;
        bool vx0 = (unsigned)ix0 < (unsigned)WW;
        bool vx1 = (unsigned)(ix0 + 1) < (unsigned)WW;
        int cy0 = min(max(iy0, 0), HH - 1), cy1 = min(max(iy0 + 1, 0), HH - 1);
        int cx0 = min(max(ix0, 0), WW - 1), cx1 = min(max(ix0 + 1, 0), WW - 1);
        float wy0 = 1.f - ty, wx0 = 1.f - tx;
        ushort w00 = h_bits(wy0 * wx0 * ((vy0 && vx0) ? 1.f : 0.f));
        ushort w01 = h_bits(wy0 * tx  * ((vy0 && vx1) ? 1.f : 0.f));
        ushort w10 = h_bits(ty  * wx0 * ((vy1 && vx0) ? 1.f : 0.f));
        ushort w11 = h_bits(ty  * tx  * ((vy1 && vx1) ? 1.f : 0.f));
        DEnt E;
        E.o00 = (b * (HH * WW) + cy0 * WW + cx0) << A.csh;
        E.dx1 = (short)((cx1 - cx0) << A.csh);
        E.dy1 = (short)(((cy1 - cy0) * WW) << A.csh);
        E.w01 = (uint)w00 | ((uint)w01 << 16);
        E.w23 = (uint)w10 | ((uint)w11 << 16);
        ent[e] = E;
    }
    __syncthreads();

    const int li  = t & 7;
    const int p   = t >> 3;
    const int ch0 = li * 8;
    const int pix = blk * 32 + p;
    const char* ibase = (const char*)(A.in + A.ci_base) + ch0 * 2;

    float acc[8];
#pragma unroll
    for (int j = 0; j < 8; j++) acc[j] = 0.f;

#pragma unroll 2
    for (int kk = 0; kk < K; kk++) {
        DEnt e = ent[p * K + kk];
        uint s00 = (e.w01 & 0xffffu) * 0x10001u;
        uint s01 = (e.w01 >> 16)     * 0x10001u;
        uint s10 = (e.w23 & 0xffffu) * 0x10001u;
        uint s11 = (e.w23 >> 16)     * 0x10001u;
        int o00 = e.o00, o01 = o00 + e.dx1, o10 = o00 + e.dy1, o11 = o10 + e.dx1;
        f16x8 c00 = *(const f16x8*)(ibase + o00);
        f16x8 c01 = *(const f16x8*)(ibase + o01);
        f16x8 c10 = *(const f16x8*)(ibase + o10);
        f16x8 c11 = *(const f16x8*)(ibase + o11);
        f16x8 s = c00 * splat8(s00);
        s = c01 * splat8(s01) + s;
        s = c10 * splat8(s10) + s;
        s = c11 * splat8(s11) + s;
        float4 d0 = *(const float4*)(A.dwT + kk * 64 + ch0);
        float4 d1 = *(const float4*)(A.dwT + kk * 64 + ch0 + 4);
        acc[0] = fmaf(d0.x, (float)s[0], acc[0]);
        acc[1] = fmaf(d0.y, (float)s[1], acc[1]);
        acc[2] = fmaf(d0.z, (float)s[2], acc[2]);
        acc[3] = fmaf(d0.w, (float)s[3], acc[3]);
        acc[4] = fmaf(d1.x, (float)s[4], acc[4]);
        acc[5] = fmaf(d1.y, (float)s[5], acc[5]);
        acc[6] = fmaf(d1.z, (float)s[6], acc[6]);
        acc[7] = fmaf(d1.w, (float)s[7], acc[7]);
    }

    f16x8 o;
#pragma unroll
    for (int j = 0; j < 8; j++) o[j] = (f16)acc[j];
    *(f16x8*)&A.out[(size_t)pix * 64 + ch0] = o;
}

template<int K1, int P1, int D1, int K2, int P2, int D2>
__global__ __launch_bounds__(256) void dsample_pair_k(DArgs A1, int nblk1, DArgs A2) {
    constexpr int KMAX = (K1 * K1 > K2 * K2) ? K1 * K1 : K2 * K2;
    __shared__ char lds[32 * KMAX * 16];
    int b = blockIdx.x;
    if (b < nblk1) dsample_body<K1, P1, D1>(b, lds, A1);
    else           dsample_body<K2, P2, D2>(b - nblk1, lds, A2);
}

// ---------------- final: out(NCHW) = x + u*attn ----------------
__global__ void final_k(const float* __restrict__ x, const f16* __restrict__ u,
                        const float* __restrict__ af, const float* __restrict__ bf,
                        float* __restrict__ out) {
    __shared__ float lu[16 * 130];
    __shared__ float lat[16 * 130];
    int t   = threadIdx.x;
    int blk = blockIdx.x;
    int wb = blk % 5;
    int r  = blk / 5;
    int h  = r % HH;
    int b  = r / HH;
    int w0 = wb * 16;
    size_t pixbase = (size_t)(b * HH + h) * WW + w0;
    for (int e = t; e < 16 * 128; e += 256) {
        int c = e & 127;
        int p = e >> 7;
        lu[p * 130 + c]  = (float)u[(pixbase + p) * 128 + c];
        lat[p * 130 + c] = (c < 64) ? af[(pixbase + p) * 64 + c]
                                    : bf[(pixbase + p) * 64 + (c - 64)];
    }
    __syncthreads();
    for (int e = t; e < 16 * 128; e += 256) {
        int p = e & 15;
        int c = e >> 4;
        size_t gi = ((size_t)(b * 128 + c) * HH + h) * WW + w0 + p;
        out[gi] = x[gi] + lu[p * 130 + c] * lat[p * 130 + c];
    }
}

extern "C" void kernel_launch(void* const* d_in, const int* in_sizes, int n_in,
                              void* d_out, int out_size, void* d_ws, size_t ws_size,
                              hipStream_t stream) {
    const float* x        = (const float*)d_in[0];
    const float* cv1_w    = (const float*)d_in[1];
    const float* bn_g     = (const float*)d_in[2];
    const float* bn_b     = (const float*)d_in[3];
    const float* bn_m     = (const float*)d_in[4];
    const float* bn_v     = (const float*)d_in[5];
    const float* a0_off_w = (const float*)d_in[6];
    const float* a0_off_b = (const float*)d_in[7];
    const float* a0_w     = (const float*)d_in[8];
    const float* a1_off_w = (const float*)d_in[9];
    const float* a1_off_b = (const float*)d_in[10];
    const float* a1_w     = (const float*)d_in[11];
    const float* b0_off_w = (const float*)d_in[12];
    const float* b0_off_b = (const float*)d_in[13];
    const float* b0_w     = (const float*)d_in[14];
    const float* b1_off_w = (const float*)d_in[15];
    const float* b1_off_b = (const float*)d_in[16];
    const float* b1_w     = (const float*)d_in[17];
    const float* conv1_w  = (const float*)d_in[18];
    const float* conv1_b  = (const float*)d_in[19];
    const float* conv2_w  = (const float*)d_in[20];
    const float* conv2_b  = (const float*)d_in[21];
    float* out = (float*)d_out;

    char* wsb = (char*)d_ws;
    size_t pos = 0;
    auto alloc = [&](size_t bytes) -> void* {
        void* p = (void*)(wsb + pos);
        pos += (bytes + 255) & ~(size_t)255;
        return p;
    };
    f16*   zbuf   = (f16*)  alloc(256);
    f16*   xb     = (f16*)  alloc((size_t)NPIX * 128 * 2);
    f16*   u      = (f16*)  alloc((size_t)NPIX * 128 * 2);
    f16*   s0a    = (f16*)  alloc((size_t)NPIX * 64 * 2);
    f16*   s0b    = (f16*)  alloc((size_t)NPIX * 64 * 2);
    f16*   s1a    = (f16*)  alloc((size_t)NPIX * 64 * 2);
    f16*   s1b    = (f16*)  alloc((size_t)NPIX * 64 * 2);
    float* offa   = (float*)alloc((size_t)NPIX * 64 * 4);   // aliased: aF written after offa dead
    float* offb   = (float*)alloc((size_t)NPIX * 128 * 4);  // aliased: bF written after offb dead
    float* aF     = offa;
    float* bF     = offb;
    f16*   pcv1   = (f16*)  alloc((size_t)36 * 8 * 512 * 2);
    f16*   pa0    = (f16*)  alloc((size_t)18 * 4 * 512 * 2);
    f16*   pa1    = (f16*)  alloc((size_t)50 * 4 * 512 * 2);
    f16*   pb0    = (f16*)  alloc((size_t)50 * 4 * 512 * 2);
    f16*   pb1    = (f16*)  alloc((size_t)98 * 8 * 512 * 2);
    f16*   pc1    = (f16*)  alloc((size_t)2  * 4 * 512 * 2);
    f16*   pc2    = (f16*)  alloc((size_t)2  * 4 * 512 * 2);
    float* dwt_a0 = (float*)alloc(9  * 64 * 4);
    float* dwt_a1 = (float*)alloc(25 * 64 * 4);
    float* dwt_b0 = (float*)alloc(25 * 64 * 4);
    float* dwt_b1 = (float*)alloc(49 * 64 * 4);

    hipMemsetAsync(zbuf, 0, 256, stream);
    xcvt_k<<<dim3(BB * HH * 5), dim3(256), 0, stream>>>(x, xb);

    auto pk = [&](const float* src, f16* dst, int cout, int cin, int kk2, int nt, int nk) {
        int total = nk * nt * 512;
        int g = (total + 255) / 256; if (g > 1024) g = 1024;
        pack_w_f16<<<dim3(g), dim3(256), 0, stream>>>(src, dst, cout, cin, kk2, nt, nk);
    };
    pk(cv1_w,    pcv1, 128, 128, 9,  8, 36);
    pk(a0_off_w, pa0,  18,  64,  9,  4, 18);
    pk(a1_off_w, pa1,  50,  64,  25, 4, 50);
    pk(b0_off_w, pb0,  50,  64,  25, 4, 50);
    pk(b1_off_w, pb1,  98,  64,  49, 8, 98);
    pk(conv1_w,  pc1,  64,  64,  1,  4, 2);
    pk(conv2_w,  pc2,  64,  64,  1,  4, 2);

    auto tw = [&](const float* src, float* dst, int O, int Opad, int I, int KK) {
        int n = KK * I * Opad;
        transpose_w_k<<<dim3((n + 255) / 256), dim3(256), 0, stream>>>(src, dst, O, Opad, I, KK);
    };
    tw(a0_w, dwt_a0, 64, 64, 1, 9);
    tw(a1_w, dwt_a1, 64, 64, 1, 25);
    tw(b0_w, dwt_b0, 64, 64, 1, 25);
    tw(b1_w, dwt_b1, 64, 64, 1, 49);

    auto margs = [&](const f16* in, int cin_tot, int ci_base, const f16* wp, int nt_tot,
                     const float* bias, int cout, int out_stride, int pad, int dil,
                     float* outf, f16* outh) {
        MArgs A;
        A.in = in; A.wp = wp; A.bias = bias; A.outf = outf; A.outh = outh;
        A.bn_g = bn_g; A.bn_b = bn_b; A.bn_m = bn_m; A.bn_v = bn_v; A.zbuf = zbuf;
        A.cin_tot = cin_tot; A.ci_base = ci_base; A.nt_tot = nt_tot; A.cout = cout;
        A.out_stride = out_stride; A.pad = pad; A.dil = dil;
        return A;
    };
    auto dargs = [&](const f16* in, int csh, int ci_base, const float* off, int off_stride,
                     const float* dwT, f16* outp) {
        DArgs A;
        A.in = in; A.off = off; A.dwT = dwT; A.out = outp;
        A.csh = csh; A.ci_base = ci_base; A.off_stride = off_stride;
        return A;
    };

    // main 3x3 conv + BN + SiLU -> u (f16 NHWC, stride 128)
    mconv_main_k<<<dim3(800), dim3(256), 0, stream>>>(
        margs(xb, 128, 0, pcv1, 8, nullptr, 128, 128, 1, 1, nullptr, u));

    // offset convs a0 + b0 (both read u)
    mconv_pair_k<3, 64, 5, 64><<<dim3(800), dim3(256), 0, stream>>>(
        margs(u, 128, 0,  pa0, 4, a0_off_b, 18, 64, 1, 1, offa, nullptr), 400,
        margs(u, 128, 64, pb0, 4, b0_off_b, 50, 64, 2, 1, offb, nullptr));

    // dsample a0 (k3) + b0 (k5)
    dsample_pair_k<3, 1, 1, 5, 2, 1><<<dim3(1600), dim3(256), 0, stream>>>(
        dargs(u, 8, 0,  offa, 64, dwt_a0, s0a), 800,
        dargs(u, 8, 64, offb, 64, dwt_b0, s0b));

    // offset convs a1 (k5) + b1 (k7)
    mconv_pair_k<5, 64, 7, 64><<<dim3(1200), dim3(256), 0, stream>>>(
        margs(s0a, 64, 0, pa1, 4, a1_off_b, 50, 64,  6, 3, offa, nullptr), 400,
        margs(s0b, 64, 0, pb1, 8, b1_off_b, 98, 128, 9, 3, offb, nullptr));

    // dsample a1 (k5) + b1 (k7)
    dsample_pair_k<5, 6, 3, 7, 9, 3><<<dim3(1600), dim3(256), 0, stream>>>(
        dargs(s0a, 7, 0, offa, 64,  dwt_a1, s1a), 800,
        dargs(s0b, 7, 0, offb, 128, dwt_b1, s1b));

    // 1x1 convs a + b  (aF aliases offa, bF aliases offb — offs are dead here)
    mconv_pair_k<1, 64, 1, 64><<<dim3(800), dim3(256), 0, stream>>>(
        margs(s1a, 64, 0, pc1, 4, conv1_b, 64, 64, 0, 1, aF, nullptr), 400,
        margs(s1b, 64, 0, pc2, 4, conv2_b, 64, 64, 0, 1, bF, nullptr));

    // final: out = x + u * attn
    final_k<<<dim3(BB * HH * 5), dim3(256), 0, stream>>>(x, u, aF, bF, out);
}

// Round 5
// 302.015 us; speedup vs baseline: 12.5698x; 1.0409x over previous
//
#include <hip/hip_runtime.h>

#define HH 80
#define WW 80
#define BB 4
#define NPIX (BB*HH*WW)

typedef _Float16 f16;
typedef _Float16 f16x8 __attribute__((ext_vector_type(8)));
typedef float    f32x4 __attribute__((ext_vector_type(4)));
typedef unsigned int uint;
typedef unsigned short ushort;

__device__ inline f16x8 splat8(uint u) {
    uint4 q = {u, u, u, u};
    return __builtin_bit_cast(f16x8, q);
}
__device__ inline ushort h_bits(float w) {
    f16 h = (f16)w;
    return __builtin_bit_cast(ushort, h);
}
__device__ inline int swiz400(int m) { return (m & 7) * 50 + (m >> 3); }
__device__ inline int swiz800(int m) { return (m & 7) * 100 + (m >> 3); }

// ---------------- f32 transpose for small weights ----------------
__global__ void transpose_w_k(const float* __restrict__ src, float* __restrict__ dst,
                              int O, int Opad, int I, int KK) {
    int n = KK * I * Opad;
    for (int idx = blockIdx.x * 256 + threadIdx.x; idx < n; idx += gridDim.x * 256) {
        int o = idx % Opad;
        int r = idx / Opad;
        int i = r % I;
        int t = r / I;
        dst[idx] = (o < O) ? src[((size_t)o * I + i) * KK + t] : 0.f;
    }
}

// ---------------- pack conv weights OIHW f32 -> MFMA B-frag layout f16 ----------------
// [ks][ct][lane][8]: element = W[n=ct*16+(l&15)][ci][tap], k = ks*32+(l>>4)*8+j
__global__ void pack_w_f16(const float* __restrict__ src, f16* __restrict__ dst,
                           int cout, int cin, int kk2, int nt_tot, int nk) {
    int total = nk * nt_tot * 512;
    for (int idx = blockIdx.x * 256 + threadIdx.x; idx < total; idx += gridDim.x * 256) {
        int j = idx & 7;
        int l = (idx >> 3) & 63;
        int rr = idx >> 9;
        int ct = rr % nt_tot;
        int ks = rr / nt_tot;
        int kkk = ks * 32 + (l >> 4) * 8 + j;
        int tap = kkk / cin;
        int ci  = kkk % cin;
        int n = ct * 16 + (l & 15);
        float v = (n < cout) ? src[((size_t)n * cin + ci) * kk2 + tap] : 0.f;
        dst[idx] = (f16)v;
    }
}

// ---------------- x (NCHW f32) -> xb (NHWC f16) ----------------
__global__ void xcvt_k(const float* __restrict__ x, f16* __restrict__ xb) {
    __shared__ float l[128 * 17];
    int t = threadIdx.x;
    int blk = blockIdx.x;
    int wb = blk % 5;
    int r  = blk / 5;
    int h  = r % HH;
    int b  = r / HH;
    int w0 = wb * 16;
    size_t pixbase = (size_t)(b * HH + h) * WW + w0;
    for (int e = t; e < 2048; e += 256) {
        int c = e >> 4, p = e & 15;
        l[c * 17 + p] = x[((size_t)(b * 128 + c)) * (HH * WW) + h * WW + w0 + p];
    }
    __syncthreads();
    for (int e = t; e < 2048; e += 256) {
        int c = e & 127, p = e >> 7;
        xb[(pixbase + p) * 128 + c] = (f16)l[c * 17 + p];
    }
}

// ---------------- MFMA implicit-GEMM conv, barrier-free, 2-deep reg pipeline ----------------
struct MArgs {
    const f16* in; const f16* wp; const float* bias;
    float* outf; f16* outh;
    const float* bn_g; const float* bn_b; const float* bn_m; const float* bn_v;
    const f16* zbuf;
    int cin_tot, ci_base, nt_tot, cout, out_stride, pad, dil;
};

template<int K, int CIN, int NT, bool OUT_F16, bool BNSILU>
__device__ __forceinline__ void mconv_body(int bx, int by, const MArgs A) {
    constexpr int SPT = CIN / 32;          // power of 2 (2 or 4)
    constexpr int NK  = K * K * SPT;       // even for all our convs
    const int t    = threadIdx.x;
    const int lane = t & 63;
    const int wv   = t >> 6;
    const int blkpix = bx * 64;
    const int ntb    = by * NT;

    const int ml = wv * 16 + (lane & 15);
    int pix  = blkpix + ml;
    int pb   = pix / (HH * WW);
    int prem = pix - pb * (HH * WW);
    int ph   = prem / WW;
    int pw   = prem - ph * WW;
    const f16* inb = A.in + (size_t)pb * (HH * WW) * A.cin_tot + A.ci_base + (lane >> 4) * 8;
    const f16* wB  = A.wp + (size_t)ntb * 512 + lane * 8;
    const int ntstep = A.nt_tot * 512;

    auto aptr = [&](int ks) -> const f16* {
        int tap = ks / SPT;                // shift
        int s   = ks & (SPT - 1);
        int ky = tap / K, kx = tap - ky * K;   // magic-mul for K=3,5,7
        int y = ph + ky * A.dil - A.pad;
        int x = pw + kx * A.dil - A.pad;
        bool v = ((unsigned)y < (unsigned)HH) & ((unsigned)x < (unsigned)WW);
        return v ? inb + ((size_t)(y * WW + x)) * A.cin_tot + s * 32 : A.zbuf;
    };

    f16x8 a[2];
    f16x8 b[2][NT];
#pragma unroll
    for (int i = 0; i < 2; i++) {
        a[i] = *(const f16x8*)aptr(i);
        const f16x8* bp = (const f16x8*)(wB + (size_t)i * ntstep);
#pragma unroll
        for (int n = 0; n < NT; n++) b[i][n] = bp[n * 64];
    }

    f32x4 acc[NT];
#pragma unroll
    for (int n = 0; n < NT; n++) acc[n] = (f32x4){0.f, 0.f, 0.f, 0.f};

#pragma unroll 2
    for (int ks = 0; ks < NK; ks++) {
        const int sl = ks & 1;
#pragma unroll
        for (int n = 0; n < NT; n++)
            acc[n] = __builtin_amdgcn_mfma_f32_16x16x32_f16(a[sl], b[sl][n], acc[n], 0, 0, 0);
        if (ks + 2 < NK) {
            a[sl] = *(const f16x8*)aptr(ks + 2);
            const f16x8* bp = (const f16x8*)(wB + (size_t)(ks + 2) * ntstep);
#pragma unroll
            for (int n = 0; n < NT; n++) b[sl][n] = bp[n * 64];
        }
    }

    const int nloc = lane & 15;
    const int prow = blkpix + wv * 16 + (lane >> 4) * 4;
#pragma unroll
    for (int ct = 0; ct < NT; ct++) {
        int n = (ntb + ct) * 16 + nloc;
        if (n >= A.cout) continue;
        float sc = 1.f, sh = 0.f, bv = 0.f;
        if (BNSILU) {
            sc = A.bn_g[n] / sqrtf(A.bn_v[n] + 1e-5f);
            sh = A.bn_b[n] - A.bn_m[n] * sc;
        } else if (A.bias) {
            bv = A.bias[n];
        }
#pragma unroll
        for (int r = 0; r < 4; r++) {
            float vv = acc[ct][r] + bv;
            if (BNSILU) { vv = vv * sc + sh; vv = vv / (1.f + expf(-vv)); }
            size_t o = (size_t)(prow + r) * A.out_stride + n;
            if (OUT_F16) A.outh[o] = (f16)vv; else A.outf[o] = vv;
        }
    }
}

__global__ __launch_bounds__(256, 4) void mconv_main_k(MArgs A) {
    int b = blockIdx.x;
    mconv_body<3, 128, 4, true, true>(swiz400(b % 400), b / 400, A);
}

template<int K1, int C1, int N1, int K2, int C2, int N2>
__global__ __launch_bounds__(256, 4) void mconv_pair_k(MArgs A1, int nblk1, MArgs A2) {
    int b = blockIdx.x;
    if (b < nblk1) {
        mconv_body<K1, C1, N1, false, false>(swiz400(b % 400), b / 400, A1);
    } else {
        int bb = b - nblk1;
        mconv_body<K2, C2, N2, false, false>(swiz400(bb % 400), bb / 400, A2);
    }
}

// ---------------- deformable sample, two-phase, 16B LDS entries ----------------
struct DArgs {
    const f16* in; const float* off; const float* dwT; f16* out;
    int csh, ci_base, off_stride;
};
struct alignas(16) DEnt { int o00; short dx1, dy1; uint w01, w23; };

template<int KS, int PAD, int DIL>
__device__ __forceinline__ void dsample_body(int blk, char* ldsraw, const DArgs A) {
    constexpr int K = KS * KS;
    DEnt* ent = (DEnt*)ldsraw;
    const int t = threadIdx.x;

    for (int e = t; e < 32 * K; e += 256) {
        int p  = e / K;
        int kk = e - p * K;
        int pix = blk * 32 + p;
        int b   = pix / (HH * WW);
        int rem = pix - b * (HH * WW);
        int h   = rem / WW;
        int w   = rem - h * WW;
        int ky = kk / KS, kx = kk - ky * KS;
        float2 d = *(const float2*)&A.off[(size_t)pix * A.off_stride + 2 * kk];
        float py = (float)(h + ky * DIL - PAD) + d.x;
        float px = (float)(w + kx * DIL - PAD) + d.y;
        float y0f = floorf(py), x0f = floorf(px);
        float ty = py - y0f, tx = px - x0f;
        int iy0 = (int)y0f, ix0 = (int)x0f;
        bool vy0 = (unsigned)iy0 < (unsigned)HH;
        bool vy1 = (unsigned)(iy0 + 1) < (unsigned)HH;
        bool vx0 = (unsigned)ix0 < (unsigned)WW;
        bool vx1 = (unsigned)(ix0 + 1) < (unsigned)WW;
        int cy0 = min(max(iy0, 0), HH - 1), cy1 = min(max(iy0 + 1, 0), HH - 1);
        int cx0 = min(max(ix0, 0), WW - 1), cx1 = min(max(ix0 + 1, 0), WW - 1);
        float wy0 = 1.f - ty, wx0 = 1.f - tx;
        ushort w00 = h_bits(wy0 * wx0 * ((vy0 && vx0) ? 1.f : 0.f));
        ushort w01 = h_bits(wy0 * tx  * ((vy0 && vx1) ? 1.f : 0.f));
        ushort w10 = h_bits(ty  * wx0 * ((vy1 && vx0) ? 1.f : 0.f));
        ushort w11 = h_bits(ty  * tx  * ((vy1 && vx1) ? 1.f : 0.f));
        DEnt E;
        E.o00 = (b * (HH * WW) + cy0 * WW + cx0) << A.csh;
        E.dx1 = (short)((cx1 - cx0) << A.csh);
        E.dy1 = (short)(((cy1 - cy0) * WW) << A.csh);
        E.w01 = (uint)w00 | ((uint)w01 << 16);
        E.w23 = (uint)w10 | ((uint)w11 << 16);
        ent[e] = E;
    }
    __syncthreads();

    const int li  = t & 7;
    const int p   = t >> 3;
    const int ch0 = li * 8;
    const int pix = blk * 32 + p;
    const char* ibase = (const char*)(A.in + A.ci_base) + ch0 * 2;

    float acc[8];
#pragma unroll
    for (int j = 0; j < 8; j++) acc[j] = 0.f;

#pragma unroll 2
    for (int kk = 0; kk < K; kk++) {
        DEnt e = ent[p * K + kk];
        uint s00 = (e.w01 & 0xffffu) * 0x10001u;
        uint s01 = (e.w01 >> 16)     * 0x10001u;
        uint s10 = (e.w23 & 0xffffu) * 0x10001u;
        uint s11 = (e.w23 >> 16)     * 0x10001u;
        int o00 = e.o00, o01 = o00 + e.dx1, o10 = o00 + e.dy1, o11 = o10 + e.dx1;
        f16x8 c00 = *(const f16x8*)(ibase + o00);
        f16x8 c01 = *(const f16x8*)(ibase + o01);
        f16x8 c10 = *(const f16x8*)(ibase + o10);
        f16x8 c11 = *(const f16x8*)(ibase + o11);
        f16x8 s = c00 * splat8(s00);
        s = c01 * splat8(s01) + s;
        s = c10 * splat8(s10) + s;
        s = c11 * splat8(s11) + s;
        float4 d0 = *(const float4*)(A.dwT + kk * 64 + ch0);
        float4 d1 = *(const float4*)(A.dwT + kk * 64 + ch0 + 4);
        acc[0] = fmaf(d0.x, (float)s[0], acc[0]);
        acc[1] = fmaf(d0.y, (float)s[1], acc[1]);
        acc[2] = fmaf(d0.z, (float)s[2], acc[2]);
        acc[3] = fmaf(d0.w, (float)s[3], acc[3]);
        acc[4] = fmaf(d1.x, (float)s[4], acc[4]);
        acc[5] = fmaf(d1.y, (float)s[5], acc[5]);
        acc[6] = fmaf(d1.z, (float)s[6], acc[6]);
        acc[7] = fmaf(d1.w, (float)s[7], acc[7]);
    }

    f16x8 o;
#pragma unroll
    for (int j = 0; j < 8; j++) o[j] = (f16)acc[j];
    *(f16x8*)&A.out[(size_t)pix * 64 + ch0] = o;
}

template<int K1, int P1, int D1, int K2, int P2, int D2>
__global__ __launch_bounds__(256) void dsample_pair_k(DArgs A1, int nblk1, DArgs A2) {
    constexpr int KMAX = (K1 * K1 > K2 * K2) ? K1 * K1 : K2 * K2;
    __shared__ char lds[32 * KMAX * 16];
    int b = blockIdx.x;
    if (b < nblk1) dsample_body<K1, P1, D1>(swiz800(b), lds, A1);
    else           dsample_body<K2, P2, D2>(swiz800(b - nblk1), lds, A2);
}

// ---------------- final: out(NCHW) = x + u*attn ----------------
__global__ void final_k(const float* __restrict__ x, const f16* __restrict__ u,
                        const float* __restrict__ af, const float* __restrict__ bf,
                        float* __restrict__ out) {
    __shared__ float lu[16 * 130];
    __shared__ float lat[16 * 130];
    int t   = threadIdx.x;
    int blk = blockIdx.x;
    int wb = blk % 5;
    int r  = blk / 5;
    int h  = r % HH;
    int b  = r / HH;
    int w0 = wb * 16;
    size_t pixbase = (size_t)(b * HH + h) * WW + w0;
    for (int e = t; e < 16 * 128; e += 256) {
        int c = e & 127;
        int p = e >> 7;
        lu[p * 130 + c]  = (float)u[(pixbase + p) * 128 + c];
        lat[p * 130 + c] = (c < 64) ? af[(pixbase + p) * 64 + c]
                                    : bf[(pixbase + p) * 64 + (c - 64)];
    }
    __syncthreads();
    for (int e = t; e < 16 * 128; e += 256) {
        int p = e & 15;
        int c = e >> 4;
        size_t gi = ((size_t)(b * 128 + c) * HH + h) * WW + w0 + p;
        out[gi] = x[gi] + lu[p * 130 + c] * lat[p * 130 + c];
    }
}

extern "C" void kernel_launch(void* const* d_in, const int* in_sizes, int n_in,
                              void* d_out, int out_size, void* d_ws, size_t ws_size,
                              hipStream_t stream) {
    const float* x        = (const float*)d_in[0];
    const float* cv1_w    = (const float*)d_in[1];
    const float* bn_g     = (const float*)d_in[2];
    const float* bn_b     = (const float*)d_in[3];
    const float* bn_m     = (const float*)d_in[4];
    const float* bn_v     = (const float*)d_in[5];
    const float* a0_off_w = (const float*)d_in[6];
    const float* a0_off_b = (const float*)d_in[7];
    const float* a0_w     = (const float*)d_in[8];
    const float* a1_off_w = (const float*)d_in[9];
    const float* a1_off_b = (const float*)d_in[10];
    const float* a1_w     = (const float*)d_in[11];
    const float* b0_off_w = (const float*)d_in[12];
    const float* b0_off_b = (const float*)d_in[13];
    const float* b0_w     = (const float*)d_in[14];
    const float* b1_off_w = (const float*)d_in[15];
    const float* b1_off_b = (const float*)d_in[16];
    const float* b1_w     = (const float*)d_in[17];
    const float* conv1_w  = (const float*)d_in[18];
    const float* conv1_b  = (const float*)d_in[19];
    const float* conv2_w  = (const float*)d_in[20];
    const float* conv2_b  = (const float*)d_in[21];
    float* out = (float*)d_out;

    char* wsb = (char*)d_ws;
    size_t pos = 0;
    auto alloc = [&](size_t bytes) -> void* {
        void* p = (void*)(wsb + pos);
        pos += (bytes + 255) & ~(size_t)255;
        return p;
    };
    f16*   zbuf   = (f16*)  alloc(256);
    f16*   xb     = (f16*)  alloc((size_t)NPIX * 128 * 2);
    f16*   u      = (f16*)  alloc((size_t)NPIX * 128 * 2);
    f16*   s0a    = (f16*)  alloc((size_t)NPIX * 64 * 2);
    f16*   s0b    = (f16*)  alloc((size_t)NPIX * 64 * 2);
    f16*   s1a    = (f16*)  alloc((size_t)NPIX * 64 * 2);
    f16*   s1b    = (f16*)  alloc((size_t)NPIX * 64 * 2);
    float* offa   = (float*)alloc((size_t)NPIX * 64 * 4);   // aliased: aF written after offa dead
    float* offb   = (float*)alloc((size_t)NPIX * 128 * 4);  // aliased: bF written after offb dead
    float* aF     = offa;
    float* bF     = offb;
    f16*   pcv1   = (f16*)  alloc((size_t)36 * 8 * 512 * 2);
    f16*   pa0    = (f16*)  alloc((size_t)18 * 2 * 512 * 2);
    f16*   pa1    = (f16*)  alloc((size_t)50 * 4 * 512 * 2);
    f16*   pb0    = (f16*)  alloc((size_t)50 * 4 * 512 * 2);
    f16*   pb1    = (f16*)  alloc((size_t)98 * 8 * 512 * 2);
    f16*   pc1    = (f16*)  alloc((size_t)2  * 4 * 512 * 2);
    f16*   pc2    = (f16*)  alloc((size_t)2  * 4 * 512 * 2);
    float* dwt_a0 = (float*)alloc(9  * 64 * 4);
    float* dwt_a1 = (float*)alloc(25 * 64 * 4);
    float* dwt_b0 = (float*)alloc(25 * 64 * 4);
    float* dwt_b1 = (float*)alloc(49 * 64 * 4);

    hipMemsetAsync(zbuf, 0, 256, stream);
    xcvt_k<<<dim3(BB * HH * 5), dim3(256), 0, stream>>>(x, xb);

    auto pk = [&](const float* src, f16* dst, int cout, int cin, int kk2, int nt, int nk) {
        int total = nk * nt * 512;
        int g = (total + 255) / 256; if (g > 1024) g = 1024;
        pack_w_f16<<<dim3(g), dim3(256), 0, stream>>>(src, dst, cout, cin, kk2, nt, nk);
    };
    pk(cv1_w,    pcv1, 128, 128, 9,  8, 36);
    pk(a0_off_w, pa0,  18,  64,  9,  2, 18);
    pk(a1_off_w, pa1,  50,  64,  25, 4, 50);
    pk(b0_off_w, pb0,  50,  64,  25, 4, 50);
    pk(b1_off_w, pb1,  98,  64,  49, 8, 98);
    pk(conv1_w,  pc1,  64,  64,  1,  4, 2);
    pk(conv2_w,  pc2,  64,  64,  1,  4, 2);

    auto tw = [&](const float* src, float* dst, int O, int Opad, int I, int KK) {
        int n = KK * I * Opad;
        transpose_w_k<<<dim3((n + 255) / 256), dim3(256), 0, stream>>>(src, dst, O, Opad, I, KK);
    };
    tw(a0_w, dwt_a0, 64, 64, 1, 9);
    tw(a1_w, dwt_a1, 64, 64, 1, 25);
    tw(b0_w, dwt_b0, 64, 64, 1, 25);
    tw(b1_w, dwt_b1, 64, 64, 1, 49);

    auto margs = [&](const f16* in, int cin_tot, int ci_base, const f16* wp, int nt_tot,
                     const float* bias, int cout, int out_stride, int pad, int dil,
                     float* outf, f16* outh) {
        MArgs A;
        A.in = in; A.wp = wp; A.bias = bias; A.outf = outf; A.outh = outh;
        A.bn_g = bn_g; A.bn_b = bn_b; A.bn_m = bn_m; A.bn_v = bn_v; A.zbuf = zbuf;
        A.cin_tot = cin_tot; A.ci_base = ci_base; A.nt_tot = nt_tot; A.cout = cout;
        A.out_stride = out_stride; A.pad = pad; A.dil = dil;
        return A;
    };
    auto dargs = [&](const f16* in, int csh, int ci_base, const float* off, int off_stride,
                     const float* dwT, f16* outp) {
        DArgs A;
        A.in = in; A.off = off; A.dwT = dwT; A.out = outp;
        A.csh = csh; A.ci_base = ci_base; A.off_stride = off_stride;
        return A;
    };

    // main 3x3 conv + BN + SiLU -> u (f16 NHWC, stride 128)
    mconv_main_k<<<dim3(800), dim3(256), 0, stream>>>(
        margs(xb, 128, 0, pcv1, 8, nullptr, 128, 128, 1, 1, nullptr, u));

    // offset convs a0 (NT=2) + b0 (NT=4)
    mconv_pair_k<3, 64, 2, 5, 64, 4><<<dim3(800), dim3(256), 0, stream>>>(
        margs(u, 128, 0,  pa0, 2, a0_off_b, 18, 64, 1, 1, offa, nullptr), 400,
        margs(u, 128, 64, pb0, 4, b0_off_b, 50, 64, 2, 1, offb, nullptr));

    // dsample a0 (k3) + b0 (k5)
    dsample_pair_k<3, 1, 1, 5, 2, 1><<<dim3(1600), dim3(256), 0, stream>>>(
        dargs(u, 8, 0,  offa, 64, dwt_a0, s0a), 800,
        dargs(u, 8, 64, offb, 64, dwt_b0, s0b));

    // offset convs a1 (k5) + b1 (k7, by split)
    mconv_pair_k<5, 64, 4, 7, 64, 4><<<dim3(1200), dim3(256), 0, stream>>>(
        margs(s0a, 64, 0, pa1, 4, a1_off_b, 50, 64,  6, 3, offa, nullptr), 400,
        margs(s0b, 64, 0, pb1, 8, b1_off_b, 98, 128, 9, 3, offb, nullptr));

    // dsample a1 (k5) + b1 (k7)
    dsample_pair_k<5, 6, 3, 7, 9, 3><<<dim3(1600), dim3(256), 0, stream>>>(
        dargs(s0a, 7, 0, offa, 64,  dwt_a1, s1a), 800,
        dargs(s0b, 7, 0, offb, 128, dwt_b1, s1b));

    // 1x1 convs a + b  (aF aliases offa, bF aliases offb — offs dead here)
    mconv_pair_k<1, 64, 4, 1, 64, 4><<<dim3(800), dim3(256), 0, stream>>>(
        margs(s1a, 64, 0, pc1, 4, conv1_b, 64, 64, 0, 1, aF, nullptr), 400,
        margs(s1b, 64, 0, pc2, 4, conv2_b, 64, 64, 0, 1, bF, nullptr));

    // final: out = x + u * attn
    final_k<<<dim3(BB * HH * 5), dim3(256), 0, stream>>>(x, u, aF, bF, out);
}

// Round 6
// 278.722 us; speedup vs baseline: 13.6203x; 1.0836x over previous
//
#include <hip/hip_runtime.h>

#define HH 80
#define WW 80
#define BB 4
#define NPIX (BB*HH*WW)

typedef _Float16 f16;
typedef _Float16 f16x8 __attribute__((ext_vector_type(8)));
typedef float    f32x4 __attribute__((ext_vector_type(4)));
typedef unsigned int uint;
typedef unsigned short ushort;

__device__ inline f16x8 splat8(uint u) {
    uint4 q = {u, u, u, u};
    return __builtin_bit_cast(f16x8, q);
}
__device__ inline ushort h_bits(float w) {
    f16 h = (f16)w;
    return __builtin_bit_cast(ushort, h);
}
__device__ inline int swiz200(int m) { return (m & 7) * 25 + (m >> 3); }
__device__ inline int swiz800(int m) { return (m & 7) * 100 + (m >> 3); }

// ---------------- f32 transpose for small weights ----------------
__global__ void transpose_w_k(const float* __restrict__ src, float* __restrict__ dst,
                              int O, int Opad, int I, int KK) {
    int n = KK * I * Opad;
    for (int idx = blockIdx.x * 256 + threadIdx.x; idx < n; idx += gridDim.x * 256) {
        int o = idx % Opad;
        int r = idx / Opad;
        int i = r % I;
        int t = r / I;
        dst[idx] = (o < O) ? src[((size_t)o * I + i) * KK + t] : 0.f;
    }
}

// ---------------- pack conv weights OIHW f32 -> MFMA B-frag layout f16 ----------------
// [ks][ct][lane][8]: element = W[n=ct*16+(l&15)][ci][tap], k = ks*32+(l>>4)*8+j
__global__ void pack_w_f16(const float* __restrict__ src, f16* __restrict__ dst,
                           int cout, int cin, int kk2, int nt_tot, int nk) {
    int total = nk * nt_tot * 512;
    for (int idx = blockIdx.x * 256 + threadIdx.x; idx < total; idx += gridDim.x * 256) {
        int j = idx & 7;
        int l = (idx >> 3) & 63;
        int rr = idx >> 9;
        int ct = rr % nt_tot;
        int ks = rr / nt_tot;
        int kkk = ks * 32 + (l >> 4) * 8 + j;
        int tap = kkk / cin;
        int ci  = kkk % cin;
        int n = ct * 16 + (l & 15);
        float v = (n < cout) ? src[((size_t)n * cin + ci) * kk2 + tap] : 0.f;
        dst[idx] = (f16)v;
    }
}

// ---------------- x (NCHW f32) -> xb (NHWC f16) ----------------
__global__ void xcvt_k(const float* __restrict__ x, f16* __restrict__ xb) {
    __shared__ float l[128 * 17];
    int t = threadIdx.x;
    int blk = blockIdx.x;
    int wb = blk % 5;
    int r  = blk / 5;
    int h  = r % HH;
    int b  = r / HH;
    int w0 = wb * 16;
    size_t pixbase = (size_t)(b * HH + h) * WW + w0;
    for (int e = t; e < 2048; e += 256) {
        int c = e >> 4, p = e & 15;
        l[c * 17 + p] = x[((size_t)(b * 128 + c)) * (HH * WW) + h * WW + w0 + p];
    }
    __syncthreads();
    for (int e = t; e < 2048; e += 256) {
        int c = e & 127, p = e >> 7;
        xb[(pixbase + p) * 128 + c] = (f16)l[c * 17 + p];
    }
}

// ---------------- MFMA implicit-GEMM conv: chunk-ring pipeline, M=32/wave ----------------
// chunk = 64 input channels (2 MFMA K-steps). Per chunk per wave:
//   4 A-loads (2 frags x 2 steps) + 2*NT B-loads -> 2*2*NT MFMAs.
// Ring depth 2 over chunks, all slot indices static (unroll 2, constexpr trip count).
struct MArgs {
    const f16* in; const f16* wp; const float* bias;
    float* outf; f16* outh;
    const float* bn_g; const float* bn_b; const float* bn_m; const float* bn_v;
    const f16* zbuf;
    int cin_tot, ci_base, nt_tot, cout, out_stride, pad, dil;
};

template<int K, int CIN, int NT, bool OUT_F16, bool BNSILU>
__device__ __forceinline__ void mconv_body(int bx, int by, const MArgs& A) {
    constexpr int CPT = CIN / 64;        // chunks per tap: 1 (CIN=64) or 2 (CIN=128)
    constexpr int NCH = K * K * CPT;     // total chunks
    const int t    = threadIdx.x;
    const int lane = t & 63;
    const int wv   = t >> 6;
    const int blkpix = bx * 128;
    const int ntb    = by * NT;
    const int ntstep = A.nt_tot * 512;   // f16 per K-step of packed B

    int ph[2], pw[2];
    const f16* inb[2];
#pragma unroll
    for (int m = 0; m < 2; m++) {
        int pix = blkpix + wv * 32 + m * 16 + (lane & 15);
        int pb  = pix / (HH * WW);
        int rem = pix - pb * (HH * WW);
        ph[m] = rem / WW;
        pw[m] = rem - ph[m] * WW;
        inb[m] = A.in + (size_t)pb * (HH * WW) * A.cin_tot + A.ci_base + (lane >> 4) * 8;
    }
    const f16* wB = A.wp + (size_t)ntb * 512 + lane * 8;

    auto aaddr = [&](int c, int m) -> const f16* {
        int tap = (CPT == 2) ? (c >> 1) : c;
        int ch0 = (CPT == 2) ? ((c & 1) * 64) : 0;
        int ky = tap / K, kx = tap - ky * K;
        int y = ph[m] + ky * A.dil - A.pad;
        int x = pw[m] + kx * A.dil - A.pad;
        bool v = ((unsigned)y < (unsigned)HH) & ((unsigned)x < (unsigned)WW);
        return v ? inb[m] + ((size_t)(y * WW + x)) * A.cin_tot + ch0 : A.zbuf;
    };

    f16x8 ar[2][2][2];    // [slot][frag][step]
    f16x8 br[2][2][NT];   // [slot][step][ntile]

    auto loadc = [&](int c, int sl) {
#pragma unroll
        for (int m = 0; m < 2; m++) {
            const f16* p = aaddr(c, m);
            ar[sl][m][0] = *(const f16x8*)p;
            ar[sl][m][1] = *(const f16x8*)(p + 32);
        }
        const f16* bc = wB + (size_t)(2 * c) * ntstep;
#pragma unroll
        for (int s = 0; s < 2; s++)
#pragma unroll
            for (int n = 0; n < NT; n++)
                br[sl][s][n] = *(const f16x8*)(bc + s * ntstep + n * 512);
    };

    f32x4 acc[2][NT] = {};
    auto comp = [&](int sl) {
#pragma unroll
        for (int s = 0; s < 2; s++)
#pragma unroll
            for (int m = 0; m < 2; m++)
#pragma unroll
                for (int n = 0; n < NT; n++)
                    acc[m][n] = __builtin_amdgcn_mfma_f32_16x16x32_f16(
                        ar[sl][m][s], br[sl][s][n], acc[m][n], 0, 0, 0);
    };

    loadc(0, 0);
    if (NCH > 1) loadc(1, 1);
#pragma unroll 2
    for (int c = 0; c < NCH; c++) {
        const int sl = c & 1;
        comp(sl);
        if (c + 2 < NCH) loadc(c + 2, sl);
    }

    const int nloc = lane & 15;
#pragma unroll
    for (int m = 0; m < 2; m++) {
        const int prow = blkpix + wv * 32 + m * 16 + (lane >> 4) * 4;
#pragma unroll
        for (int ct = 0; ct < NT; ct++) {
            int n = (ntb + ct) * 16 + nloc;
            if (n >= A.cout) continue;
            float sc = 1.f, sh = 0.f, bv = 0.f;
            if (BNSILU) {
                sc = A.bn_g[n] / sqrtf(A.bn_v[n] + 1e-5f);
                sh = A.bn_b[n] - A.bn_m[n] * sc;
            } else if (A.bias) {
                bv = A.bias[n];
            }
#pragma unroll
            for (int r = 0; r < 4; r++) {
                float vv = acc[m][ct][r] + bv;
                if (BNSILU) { vv = vv * sc + sh; vv = vv / (1.f + expf(-vv)); }
                size_t o = (size_t)(prow + r) * A.out_stride + n;
                if (OUT_F16) A.outh[o] = (f16)vv; else A.outf[o] = vv;
            }
        }
    }
}

__global__ __launch_bounds__(256, 3) void mconv_main_k(MArgs A) {
    int b = blockIdx.x;
    mconv_body<3, 128, 4, true, true>(swiz200(b % 200), b / 200, A);
}

template<int K1, int C1, int N1, int K2, int C2, int N2>
__global__ __launch_bounds__(256, 3) void mconv_pair_k(MArgs A1, int nblk1, MArgs A2) {
    int b = blockIdx.x;
    if (b < nblk1) {
        mconv_body<K1, C1, N1, false, false>(swiz200(b % 200), b / 200, A1);
    } else {
        int bb = b - nblk1;
        mconv_body<K2, C2, N2, false, false>(swiz200(bb % 200), bb / 200, A2);
    }
}

// ---------------- deformable sample, two-phase, 16B LDS entries ----------------
struct DArgs {
    const f16* in; const float* off; const float* dwT; f16* out;
    int csh, ci_base, off_stride;
};
struct alignas(16) DEnt { int o00; short dx1, dy1; uint w01, w23; };

template<int KS, int PAD, int DIL>
__device__ __forceinline__ void dsample_body(int blk, char* ldsraw, const DArgs A) {
    constexpr int K = KS * KS;
    DEnt* ent = (DEnt*)ldsraw;
    const int t = threadIdx.x;

    for (int e = t; e < 32 * K; e += 256) {
        int p  = e / K;
        int kk = e - p * K;
        int pix = blk * 32 + p;
        int b   = pix / (HH * WW);
        int rem = pix - b * (HH * WW);
        int h   = rem / WW;
        int w   = rem - h * WW;
        int ky = kk / KS, kx = kk - ky * KS;
        float2 d = *(const float2*)&A.off[(size_t)pix * A.off_stride + 2 * kk];
        float py = (float)(h + ky * DIL - PAD) + d.x;
        float px = (float)(w + kx * DIL - PAD) + d.y;
        float y0f = floorf(py), x0f = floorf(px);
        float ty = py - y0f, tx = px - x0f;
        int iy0 = (int)y0f, ix0 = (int)x0f;
        bool vy0 = (unsigned)iy0 < (unsigned)HH;
        bool vy1 = (unsigned)(iy0 + 1) < (unsigned)HH;
        bool vx0 = (unsigned)ix0 < (unsigned)WW;
        bool vx1 = (unsigned)(ix0 + 1) < (unsigned)WW;
        int cy0 = min(max(iy0, 0), HH - 1), cy1 = min(max(iy0 + 1, 0), HH - 1);
        int cx0 = min(max(ix0, 0), WW - 1), cx1 = min(max(ix0 + 1, 0), WW - 1);
        float wy0 = 1.f - ty, wx0 = 1.f - tx;
        ushort w00 = h_bits(wy0 * wx0 * ((vy0 && vx0) ? 1.f : 0.f));
        ushort w01 = h_bits(wy0 * tx  * ((vy0 && vx1) ? 1.f : 0.f));
        ushort w10 = h_bits(ty  * wx0 * ((vy1 && vx0) ? 1.f : 0.f));
        ushort w11 = h_bits(ty  * tx  * ((vy1 && vx1) ? 1.f : 0.f));
        DEnt E;
        E.o00 = (b * (HH * WW) + cy0 * WW + cx0) << A.csh;
        E.dx1 = (short)((cx1 - cx0) << A.csh);
        E.dy1 = (short)(((cy1 - cy0) * WW) << A.csh);
        E.w01 = (uint)w00 | ((uint)w01 << 16);
        E.w23 = (uint)w10 | ((uint)w11 << 16);
        ent[e] = E;
    }
    __syncthreads();

    const int li  = t & 7;
    const int p   = t >> 3;
    const int ch0 = li * 8;
    const int pix = blk * 32 + p;
    const char* ibase = (const char*)(A.in + A.ci_base) + ch0 * 2;

    float acc[8];
#pragma unroll
    for (int j = 0; j < 8; j++) acc[j] = 0.f;

#pragma unroll 2
    for (int kk = 0; kk < K; kk++) {
        DEnt e = ent[p * K + kk];
        uint s00 = (e.w01 & 0xffffu) * 0x10001u;
        uint s01 = (e.w01 >> 16)     * 0x10001u;
        uint s10 = (e.w23 & 0xffffu) * 0x10001u;
        uint s11 = (e.w23 >> 16)     * 0x10001u;
        int o00 = e.o00, o01 = o00 + e.dx1, o10 = o00 + e.dy1, o11 = o10 + e.dx1;
        f16x8 c00 = *(const f16x8*)(ibase + o00);
        f16x8 c01 = *(const f16x8*)(ibase + o01);
        f16x8 c10 = *(const f16x8*)(ibase + o10);
        f16x8 c11 = *(const f16x8*)(ibase + o11);
        f16x8 s = c00 * splat8(s00);
        s = c01 * splat8(s01) + s;
        s = c10 * splat8(s10) + s;
        s = c11 * splat8(s11) + s;
        float4 d0 = *(const float4*)(A.dwT + kk * 64 + ch0);
        float4 d1 = *(const float4*)(A.dwT + kk * 64 + ch0 + 4);
        acc[0] = fmaf(d0.x, (float)s[0], acc[0]);
        acc[1] = fmaf(d0.y, (float)s[1], acc[1]);
        acc[2] = fmaf(d0.z, (float)s[2], acc[2]);
        acc[3] = fmaf(d0.w, (float)s[3], acc[3]);
        acc[4] = fmaf(d1.x, (float)s[4], acc[4]);
        acc[5] = fmaf(d1.y, (float)s[5], acc[5]);
        acc[6] = fmaf(d1.z, (float)s[6], acc[6]);
        acc[7] = fmaf(d1.w, (float)s[7], acc[7]);
    }

    f16x8 o;
#pragma unroll
    for (int j = 0; j < 8; j++) o[j] = (f16)acc[j];
    *(f16x8*)&A.out[(size_t)pix * 64 + ch0] = o;
}

template<int K1, int P1, int D1, int K2, int P2, int D2>
__global__ __launch_bounds__(256) void dsample_pair_k(DArgs A1, int nblk1, DArgs A2) {
    constexpr int KMAX = (K1 * K1 > K2 * K2) ? K1 * K1 : K2 * K2;
    __shared__ char lds[32 * KMAX * 16];
    int b = blockIdx.x;
    if (b < nblk1) dsample_body<K1, P1, D1>(swiz800(b), lds, A1);
    else           dsample_body<K2, P2, D2>(swiz800(b - nblk1), lds, A2);
}

// ---------------- final: out(NCHW) = x + u*attn ----------------
__global__ void final_k(const float* __restrict__ x, const f16* __restrict__ u,
                        const float* __restrict__ af, const float* __restrict__ bf,
                        float* __restrict__ out) {
    __shared__ float lu[16 * 130];
    __shared__ float lat[16 * 130];
    int t   = threadIdx.x;
    int blk = blockIdx.x;
    int wb = blk % 5;
    int r  = blk / 5;
    int h  = r % HH;
    int b  = r / HH;
    int w0 = wb * 16;
    size_t pixbase = (size_t)(b * HH + h) * WW + w0;
    for (int e = t; e < 16 * 128; e += 256) {
        int c = e & 127;
        int p = e >> 7;
        lu[p * 130 + c]  = (float)u[(pixbase + p) * 128 + c];
        lat[p * 130 + c] = (c < 64) ? af[(pixbase + p) * 64 + c]
                                    : bf[(pixbase + p) * 64 + (c - 64)];
    }
    __syncthreads();
    for (int e = t; e < 16 * 128; e += 256) {
        int p = e & 15;
        int c = e >> 4;
        size_t gi = ((size_t)(b * 128 + c) * HH + h) * WW + w0 + p;
        out[gi] = x[gi] + lu[p * 130 + c] * lat[p * 130 + c];
    }
}

extern "C" void kernel_launch(void* const* d_in, const int* in_sizes, int n_in,
                              void* d_out, int out_size, void* d_ws, size_t ws_size,
                              hipStream_t stream) {
    const float* x        = (const float*)d_in[0];
    const float* cv1_w    = (const float*)d_in[1];
    const float* bn_g     = (const float*)d_in[2];
    const float* bn_b     = (const float*)d_in[3];
    const float* bn_m     = (const float*)d_in[4];
    const float* bn_v     = (const float*)d_in[5];
    const float* a0_off_w = (const float*)d_in[6];
    const float* a0_off_b = (const float*)d_in[7];
    const float* a0_w     = (const float*)d_in[8];
    const float* a1_off_w = (const float*)d_in[9];
    const float* a1_off_b = (const float*)d_in[10];
    const float* a1_w     = (const float*)d_in[11];
    const float* b0_off_w = (const float*)d_in[12];
    const float* b0_off_b = (const float*)d_in[13];
    const float* b0_w     = (const float*)d_in[14];
    const float* b1_off_w = (const float*)d_in[15];
    const float* b1_off_b = (const float*)d_in[16];
    const float* b1_w     = (const float*)d_in[17];
    const float* conv1_w  = (const float*)d_in[18];
    const float* conv1_b  = (const float*)d_in[19];
    const float* conv2_w  = (const float*)d_in[20];
    const float* conv2_b  = (const float*)d_in[21];
    float* out = (float*)d_out;

    char* wsb = (char*)d_ws;
    size_t pos = 0;
    auto alloc = [&](size_t bytes) -> void* {
        void* p = (void*)(wsb + pos);
        pos += (bytes + 255) & ~(size_t)255;
        return p;
    };
    f16*   zbuf   = (f16*)  alloc(256);
    f16*   xb     = (f16*)  alloc((size_t)NPIX * 128 * 2);
    f16*   u      = (f16*)  alloc((size_t)NPIX * 128 * 2);
    f16*   s0a    = (f16*)  alloc((size_t)NPIX * 64 * 2);
    f16*   s0b    = (f16*)  alloc((size_t)NPIX * 64 * 2);
    f16*   s1a    = (f16*)  alloc((size_t)NPIX * 64 * 2);
    f16*   s1b    = (f16*)  alloc((size_t)NPIX * 64 * 2);
    float* offa   = (float*)alloc((size_t)NPIX * 64 * 4);   // aliased: aF written after offa dead
    float* offb   = (float*)alloc((size_t)NPIX * 128 * 4);  // aliased: bF written after offb dead
    float* aF     = offa;
    float* bF     = offb;
    f16*   pcv1   = (f16*)  alloc((size_t)36 * 8 * 512 * 2);
    f16*   pa0    = (f16*)  alloc((size_t)18 * 2 * 512 * 2);
    f16*   pa1    = (f16*)  alloc((size_t)50 * 4 * 512 * 2);
    f16*   pb0    = (f16*)  alloc((size_t)50 * 4 * 512 * 2);
    f16*   pb1    = (f16*)  alloc((size_t)98 * 8 * 512 * 2);
    f16*   pc1    = (f16*)  alloc((size_t)2  * 4 * 512 * 2);
    f16*   pc2    = (f16*)  alloc((size_t)2  * 4 * 512 * 2);
    float* dwt_a0 = (float*)alloc(9  * 64 * 4);
    float* dwt_a1 = (float*)alloc(25 * 64 * 4);
    float* dwt_b0 = (float*)alloc(25 * 64 * 4);
    float* dwt_b1 = (float*)alloc(49 * 64 * 4);

    hipMemsetAsync(zbuf, 0, 256, stream);
    xcvt_k<<<dim3(BB * HH * 5), dim3(256), 0, stream>>>(x, xb);

    auto pk = [&](const float* src, f16* dst, int cout, int cin, int kk2, int nt, int nk) {
        int total = nk * nt * 512;
        int g = (total + 255) / 256; if (g > 1024) g = 1024;
        pack_w_f16<<<dim3(g), dim3(256), 0, stream>>>(src, dst, cout, cin, kk2, nt, nk);
    };
    pk(cv1_w,    pcv1, 128, 128, 9,  8, 36);
    pk(a0_off_w, pa0,  18,  64,  9,  2, 18);
    pk(a1_off_w, pa1,  50,  64,  25, 4, 50);
    pk(b0_off_w, pb0,  50,  64,  25, 4, 50);
    pk(b1_off_w, pb1,  98,  64,  49, 8, 98);
    pk(conv1_w,  pc1,  64,  64,  1,  4, 2);
    pk(conv2_w,  pc2,  64,  64,  1,  4, 2);

    auto tw = [&](const float* src, float* dst, int O, int Opad, int I, int KK) {
        int n = KK * I * Opad;
        transpose_w_k<<<dim3((n + 255) / 256), dim3(256), 0, stream>>>(src, dst, O, Opad, I, KK);
    };
    tw(a0_w, dwt_a0, 64, 64, 1, 9);
    tw(a1_w, dwt_a1, 64, 64, 1, 25);
    tw(b0_w, dwt_b0, 64, 64, 1, 25);
    tw(b1_w, dwt_b1, 64, 64, 1, 49);

    auto margs = [&](const f16* in, int cin_tot, int ci_base, const f16* wp, int nt_tot,
                     const float* bias, int cout, int out_stride, int pad, int dil,
                     float* outf, f16* outh) {
        MArgs A;
        A.in = in; A.wp = wp; A.bias = bias; A.outf = outf; A.outh = outh;
        A.bn_g = bn_g; A.bn_b = bn_b; A.bn_m = bn_m; A.bn_v = bn_v; A.zbuf = zbuf;
        A.cin_tot = cin_tot; A.ci_base = ci_base; A.nt_tot = nt_tot; A.cout = cout;
        A.out_stride = out_stride; A.pad = pad; A.dil = dil;
        return A;
    };
    auto dargs = [&](const f16* in, int csh, int ci_base, const float* off, int off_stride,
                     const float* dwT, f16* outp) {
        DArgs A;
        A.in = in; A.off = off; A.dwT = dwT; A.out = outp;
        A.csh = csh; A.ci_base = ci_base; A.off_stride = off_stride;
        return A;
    };

    // main 3x3 conv + BN + SiLU -> u (f16 NHWC, stride 128)
    mconv_main_k<<<dim3(400), dim3(256), 0, stream>>>(
        margs(xb, 128, 0, pcv1, 8, nullptr, 128, 128, 1, 1, nullptr, u));

    // offset convs a0 (NT=2) + b0 (NT=4)
    mconv_pair_k<3, 64, 2, 5, 64, 4><<<dim3(400), dim3(256), 0, stream>>>(
        margs(u, 128, 0,  pa0, 2, a0_off_b, 18, 64, 1, 1, offa, nullptr), 200,
        margs(u, 128, 64, pb0, 4, b0_off_b, 50, 64, 2, 1, offb, nullptr));

    // dsample a0 (k3) + b0 (k5)
    dsample_pair_k<3, 1, 1, 5, 2, 1><<<dim3(1600), dim3(256), 0, stream>>>(
        dargs(u, 8, 0,  offa, 64, dwt_a0, s0a), 800,
        dargs(u, 8, 64, offb, 64, dwt_b0, s0b));

    // offset convs a1 (k5) + b1 (k7, 2 col-tiles)
    mconv_pair_k<5, 64, 4, 7, 64, 4><<<dim3(600), dim3(256), 0, stream>>>(
        margs(s0a, 64, 0, pa1, 4, a1_off_b, 50, 64,  6, 3, offa, nullptr), 200,
        margs(s0b, 64, 0, pb1, 8, b1_off_b, 98, 128, 9, 3, offb, nullptr));

    // dsample a1 (k5) + b1 (k7)
    dsample_pair_k<5, 6, 3, 7, 9, 3><<<dim3(1600), dim3(256), 0, stream>>>(
        dargs(s0a, 7, 0, offa, 64,  dwt_a1, s1a), 800,
        dargs(s0b, 7, 0, offb, 128, dwt_b1, s1b));

    // 1x1 convs a + b  (aF aliases offa, bF aliases offb — offs dead here)
    mconv_pair_k<1, 64, 4, 1, 64, 4><<<dim3(400), dim3(256), 0, stream>>>(
        margs(s1a, 64, 0, pc1, 4, conv1_b, 64, 64, 0, 1, aF, nullptr), 200,
        margs(s1b, 64, 0, pc2, 4, conv2_b, 64, 64, 0, 1, bF, nullptr));

    // final: out = x + u * attn
    final_k<<<dim3(BB * HH * 5), dim3(256), 0, stream>>>(x, u, aF, bF, out);
}